// Round 5
// baseline (710.509 us; speedup 1.0000x reference)
//
#include <hip/hip_runtime.h>

#define N_NODES 50000
#define N_EDGES 800000
#define F 128
#define K2 256

typedef unsigned short u16;
typedef __bf16 bf16x8 __attribute__((ext_vector_type(8)));
typedef float f32x4 __attribute__((ext_vector_type(4)));

__device__ inline u16 f2bf(float f) {
  union { float f; unsigned u; } v; v.f = f;
  unsigned r = v.u + 0x7fffu + ((v.u >> 16) & 1u);
  return (u16)(r >> 16);
}

__device__ inline int clampi(int v) {
  v = v < 0 ? 0 : v;
  return v >= N_NODES ? N_NODES - 1 : v;
}

// ---------- convert x (fp32) -> bf16 (staged in d_out's first half) ----------
__global__ void convert_x_kernel(const float* __restrict__ x, u16* __restrict__ xb) {
  int stride = gridDim.x * blockDim.x;
  int n = (N_NODES * F) / 8;
  for (int i = blockIdx.x * blockDim.x + threadIdx.x; i < n; i += stride) {
    const float4* px = (const float4*)x + 2 * i;
    float4 a = px[0], b = px[1];
    unsigned u0 = f2bf(a.x) | ((unsigned)f2bf(a.y) << 16);
    unsigned u1 = f2bf(a.z) | ((unsigned)f2bf(a.w) << 16);
    unsigned u2 = f2bf(b.x) | ((unsigned)f2bf(b.y) << 16);
    unsigned u3 = f2bf(b.z) | ((unsigned)f2bf(b.w) << 16);
    uint4 o; o.x = u0; o.y = u1; o.z = u2; o.w = u3;
    ((uint4*)xb)[i] = o;
  }
}

// ---------- zero degree counters ----------
__global__ void zero_deg_kernel(int* __restrict__ deg) {
  int i = blockIdx.x * blockDim.x + threadIdx.x;
  if (i < N_NODES) deg[i] = 0;
}

// ---------- histogram of dst ----------
__global__ void hist_kernel(const int* __restrict__ ei, int* __restrict__ deg) {
  int e = blockIdx.x * blockDim.x + threadIdx.x;
  if (e < N_EDGES) atomicAdd(&deg[clampi(ei[N_EDGES + e])], 1);
}

// ---------- single-block exclusive scan over 50000 degrees ----------
__global__ __launch_bounds__(1024) void scan_kernel(const int* __restrict__ deg,
                                                    int* __restrict__ offsets,
                                                    int* __restrict__ cursor) {
  __shared__ int wsum[16];
  __shared__ int sbase;
  int t = threadIdx.x, lane = t & 63, wid = t >> 6;
  if (t == 0) sbase = 0;
  __syncthreads();
  for (int base = 0; base < N_NODES; base += 1024) {
    int i = base + t;
    int v = (i < N_NODES) ? deg[i] : 0;
    int s = v;
#pragma unroll
    for (int d = 1; d < 64; d <<= 1) {
      int u = __shfl_up(s, d);
      if (lane >= d) s += u;
    }
    if (lane == 63) wsum[wid] = s;
    __syncthreads();
    if (wid == 0 && lane < 16) {
      int ws = wsum[lane];
#pragma unroll
      for (int d = 1; d < 16; d <<= 1) {
        int u = __shfl_up(ws, d);
        if (lane >= d) ws += u;
      }
      wsum[lane] = ws;
    }
    __syncthreads();
    int wprev = (wid == 0) ? 0 : wsum[wid - 1];
    int excl = sbase + wprev + s - v;
    if (i < N_NODES) { offsets[i] = excl; cursor[i] = excl; }
    __syncthreads();
    if (t == 1023) sbase = sbase + wprev + s;
    __syncthreads();
  }
  if (t == 0) offsets[N_NODES] = sbase;
}

// ---------- reorder: perm[sorted_slot] = original edge id ----------
__global__ void reorder_kernel(const int* __restrict__ ei, int* __restrict__ cursor,
                               int* __restrict__ perm) {
  int e = blockIdx.x * blockDim.x + threadIdx.x;
  if (e < N_EDGES) {
    int d = clampi(ei[N_EDGES + e]);
    int p = atomicAdd(&cursor[d], 1);
    perm[p] = e;
  }
}

// ---------- transpose weights to bf16, n-major ----------
__global__ void prep_weights_kernel(const float* __restrict__ W, const float* __restrict__ W1,
                                    u16* __restrict__ wt, u16* __restrict__ w1t) {
  int t = blockIdx.x * blockDim.x + threadIdx.x;
  if (t < 128 * 128) {
    int k = t >> 7, n = t & 127;
    wt[n * 128 + k] = f2bf(W[k * 128 + n]);
  } else {
    int t2 = t - 128 * 128;
    int k = t2 >> 7, n = t2 & 127;
    w1t[n * 256 + k] = f2bf(W1[k * 128 + n]);
  }
}

// ---------- x_t = x @ W + b  (bf16 MFMA from xb, bf16 out to ws) ----------
#define WTP 136
__global__ __launch_bounds__(256) void xform_kernel(
    const u16* __restrict__ xb, const u16* __restrict__ wt,
    const float* __restrict__ bias, u16* __restrict__ xt)
{
  __shared__ u16 wl[128 * WTP];
  for (int c = threadIdx.x; c < 128 * 16; c += 256) {
    int nrow = c >> 4, ko = (c & 15) * 8;
    *(bf16x8*)&wl[nrow * WTP + ko] = *(const bf16x8*)(wt + nrow * 128 + ko);
  }
  __syncthreads();
  int w = threadIdx.x >> 6, l = threadIdx.x & 63;
  int r2 = l & 15, q = l >> 4;
  int rowbase = blockIdx.x * 128 + w * 32;
  float bv[8];
#pragma unroll
  for (int nf = 0; nf < 8; nf++) bv[nf] = bias[r2 + 16 * nf];
  int ra0 = rowbase + r2;       if (ra0 >= N_NODES) ra0 = N_NODES - 1;
  int ra1 = rowbase + 16 + r2;  if (ra1 >= N_NODES) ra1 = N_NODES - 1;
  const u16* pa0 = xb + ra0 * F + q * 8;
  const u16* pa1 = xb + ra1 * F + q * 8;
  f32x4 acc0[8] = {}, acc1[8] = {};
#pragma unroll
  for (int k = 0; k < 4; k++) {
    bf16x8 a0 = *(const bf16x8*)(pa0 + 32 * k);
    bf16x8 a1 = *(const bf16x8*)(pa1 + 32 * k);
#pragma unroll
    for (int nf = 0; nf < 8; nf++) {
      bf16x8 b = *(const bf16x8*)&wl[(16 * nf + r2) * WTP + q * 8 + 32 * k];
      acc0[nf] = __builtin_amdgcn_mfma_f32_16x16x32_bf16(a0, b, acc0[nf], 0, 0, 0);
      acc1[nf] = __builtin_amdgcn_mfma_f32_16x16x32_bf16(a1, b, acc1[nf], 0, 0, 0);
    }
  }
#pragma unroll
  for (int nf = 0; nf < 8; nf++) {
#pragma unroll
    for (int r = 0; r < 4; r++) {
      int row0 = rowbase + 4 * q + r;
      int row1 = row0 + 16;
      int c = r2 + 16 * nf;
      if (row0 < N_NODES) xt[row0 * F + c] = f2bf(acc0[nf][r] + bv[nf]);
      if (row1 < N_NODES) xt[row1 * F + c] = f2bf(acc1[nf][r] + bv[nf]);
    }
  }
}

// ---------- gate kernel: 8-wave blocks, 16 edges/wave, bf16 gathers ----------
#define TILE_EDGES 128
__global__ __launch_bounds__(512, 4) void gate_kernel(
    const u16* __restrict__ xb, const u16* __restrict__ w1t,
    const float* __restrict__ b1, const float* __restrict__ w2f,
    const float* __restrict__ b2, const int* __restrict__ ei,
    float* __restrict__ ew)
{
  __shared__ u16 w1l[128 * 256];
  for (int c = threadIdx.x; c < 128 * 32; c += 512) {
    int nrow = c >> 5, slot = c & 31;
    *(bf16x8*)&w1l[nrow * 256 + ((slot ^ (nrow & 7)) << 3)] =
        *(const bf16x8*)(w1t + nrow * 256 + (slot << 3));
  }
  __syncthreads();
  int w = threadIdx.x >> 6, l = threadIdx.x & 63;
  int r2 = l & 15, q = l >> 4;
  int sw = r2 & 7;
  float b1v[8], w2v[8];
#pragma unroll
  for (int nf = 0; nf < 8; nf++) {
    b1v[nf] = b1[r2 + 16 * nf];
    w2v[nf] = w2f[r2 + 16 * nf];
  }
  float bias2 = b2[0];
  const int ntiles = N_EDGES / TILE_EDGES;
  for (int tile = blockIdx.x; tile < ntiles; tile += gridDim.x) {
    int ebase = tile * TILE_EDGES + w * 16;
    int s = clampi(ei[ebase + r2]);
    int d = clampi(ei[N_EDGES + ebase + r2]);
    const u16* ps = xb + s * F + q * 8;
    const u16* pd = xb + d * F + q * 8;
    f32x4 acc[8] = {};
#pragma unroll
    for (int k = 0; k < 8; k++) {
      const u16* pa = (k < 4) ? (ps + 32 * k) : (pd + 32 * (k - 4));
      bf16x8 a = *(const bf16x8*)pa;
#pragma unroll
      for (int nf = 0; nf < 8; nf++) {
        bf16x8 b = *(const bf16x8*)&w1l[(16 * nf + r2) * 256 + (((q + 4 * k) ^ sw) << 3)];
        acc[nf] = __builtin_amdgcn_mfma_f32_16x16x32_bf16(a, b, acc[nf], 0, 0, 0);
      }
    }
    float t0[4];
#pragma unroll
    for (int r = 0; r < 4; r++) {
      float sa = 0.f;
#pragma unroll
      for (int nf = 0; nf < 8; nf++) {
        float h = acc[nf][r] + b1v[nf]; h = h > 0.f ? h : 0.f;
        sa += h * w2v[nf];
      }
#pragma unroll
      for (int dd = 1; dd < 16; dd <<= 1) sa += __shfl_xor(sa, dd);
      t0[r] = sa;
    }
    if (r2 < 4) {
      float z = r2 == 0 ? t0[0] : r2 == 1 ? t0[1] : r2 == 2 ? t0[2] : t0[3];
      ew[ebase + 4 * q + r2] = 1.0f / (1.0f + __expf(-(z + bias2)));
    }
  }
}

// ---------- aggregation: one wave per dst node, no atomics, unroll 4 ----------
__global__ __launch_bounds__(256) void aggregate_kernel(
    const u16* __restrict__ xt, const int* __restrict__ offsets,
    const int* __restrict__ perm, const int* __restrict__ ei,
    const float* __restrict__ ew, float* __restrict__ out)
{
  int n = (blockIdx.x * blockDim.x + threadIdx.x) >> 6;
  int lane = threadIdx.x & 63;
  if (n >= N_NODES) return;
  int p = offsets[n], end = offsets[n + 1];
  float a0 = 0.f, a1 = 0.f;
  for (; p + 3 < end; p += 4) {
    int e0 = perm[p], e1 = perm[p + 1], e2 = perm[p + 2], e3 = perm[p + 3];
    int s0 = clampi(ei[e0]), s1 = clampi(ei[e1]);
    int s2 = clampi(ei[e2]), s3 = clampi(ei[e3]);
    float w0 = ew[e0], w1 = ew[e1], w2 = ew[e2], w3 = ew[e3];
    unsigned v0 = *(const unsigned*)(xt + s0 * F + 2 * lane);
    unsigned v1 = *(const unsigned*)(xt + s1 * F + 2 * lane);
    unsigned v2 = *(const unsigned*)(xt + s2 * F + 2 * lane);
    unsigned v3 = *(const unsigned*)(xt + s3 * F + 2 * lane);
    a0 += w0 * __uint_as_float(v0 << 16) + w1 * __uint_as_float(v1 << 16)
        + w2 * __uint_as_float(v2 << 16) + w3 * __uint_as_float(v3 << 16);
    a1 += w0 * __uint_as_float(v0 & 0xffff0000u) + w1 * __uint_as_float(v1 & 0xffff0000u)
        + w2 * __uint_as_float(v2 & 0xffff0000u) + w3 * __uint_as_float(v3 & 0xffff0000u);
  }
  for (; p < end; p++) {
    int e0 = perm[p];
    int s0 = clampi(ei[e0]);
    float w0 = ew[e0];
    unsigned v0 = *(const unsigned*)(xt + s0 * F + 2 * lane);
    a0 += w0 * __uint_as_float(v0 << 16);
    a1 += w0 * __uint_as_float(v0 & 0xffff0000u);
  }
  out[n * F + 2 * lane] = a0;
  out[n * F + 2 * lane + 1] = a1;
}

extern "C" void kernel_launch(void* const* d_in, const int* in_sizes, int n_in,
                              void* d_out, int out_size, void* d_ws, size_t ws_size,
                              hipStream_t stream) {
  const float* x  = (const float*)d_in[0];
  const int* ei   = (const int*)d_in[1];   // int64 in reference -> int32 in harness
  const float* W  = (const float*)d_in[2];
  const float* b  = (const float*)d_in[3];
  const float* W1 = (const float*)d_in[4];
  const float* b1 = (const float*)d_in[5];
  const float* W2 = (const float*)d_in[6];
  const float* b2 = (const float*)d_in[7];
  float* out = (float*)d_out;

  // bf16 copy of x lives in d_out's first 12.8 MB until aggregate overwrites it
  u16* xb = (u16*)d_out;

  char* ws = (char*)d_ws;
  u16* xt      = (u16*)ws;                    // 12,800,000 B
  u16* wt      = (u16*)(ws + 12800000);       //     32,768 B
  u16* w1t     = (u16*)(ws + 12832768);       //     65,536 B
  int* offsets = (int*)(ws + 12898304);       //    200,004 B
  int* deg     = (int*)(ws + 13098308);       //    200,000 B
  int* cursor  = (int*)(ws + 13298308);       //    200,000 B
  int* perm    = (int*)(ws + 13498308);       //  3,200,000 B
  float* ewbuf = (float*)(ws + 16698308);     //  3,200,000 B  (total ~19.9 MB)

  convert_x_kernel<<<1024, 256, 0, stream>>>(x, xb);
  zero_deg_kernel<<<(N_NODES + 255) / 256, 256, 0, stream>>>(deg);
  prep_weights_kernel<<<192, 256, 0, stream>>>(W, W1, wt, w1t);
  hist_kernel<<<(N_EDGES + 255) / 256, 256, 0, stream>>>(ei, deg);
  scan_kernel<<<1, 1024, 0, stream>>>(deg, offsets, cursor);
  reorder_kernel<<<(N_EDGES + 255) / 256, 256, 0, stream>>>(ei, cursor, perm);
  xform_kernel<<<391, 256, 0, stream>>>(xb, wt, b, xt);
  gate_kernel<<<512, 512, 0, stream>>>(xb, w1t, b1, W2, b2, ei, ewbuf);
  aggregate_kernel<<<(N_NODES * 64 + 255) / 256, 256, 0, stream>>>(xt, offsets, perm, ei, ewbuf, out);
}

// Round 6
// 372.930 us; speedup vs baseline: 1.9052x; 1.9052x over previous
//
#include <hip/hip_runtime.h>

#define N_NODES 50000
#define N_EDGES 800000
#define F 128
#define K2 256

typedef unsigned short u16;
typedef __bf16 bf16x8 __attribute__((ext_vector_type(8)));
typedef float f32x4 __attribute__((ext_vector_type(4)));

__device__ inline u16 f2bf(float f) {
  union { float f; unsigned u; } v; v.f = f;
  unsigned r = v.u + 0x7fffu + ((v.u >> 16) & 1u);
  return (u16)(r >> 16);
}

__device__ inline int clampi(int v) {
  v = v < 0 ? 0 : v;
  return v >= N_NODES ? N_NODES - 1 : v;
}

// ---------- convert x (fp32) -> bf16 (staged in d_out's first half) ----------
__global__ void convert_x_kernel(const float* __restrict__ x, u16* __restrict__ xb) {
  int stride = gridDim.x * blockDim.x;
  int n = (N_NODES * F) / 8;
  for (int i = blockIdx.x * blockDim.x + threadIdx.x; i < n; i += stride) {
    const float4* px = (const float4*)x + 2 * i;
    float4 a = px[0], b = px[1];
    unsigned u0 = f2bf(a.x) | ((unsigned)f2bf(a.y) << 16);
    unsigned u1 = f2bf(a.z) | ((unsigned)f2bf(a.w) << 16);
    unsigned u2 = f2bf(b.x) | ((unsigned)f2bf(b.y) << 16);
    unsigned u3 = f2bf(b.z) | ((unsigned)f2bf(b.w) << 16);
    uint4 o; o.x = u0; o.y = u1; o.z = u2; o.w = u3;
    ((uint4*)xb)[i] = o;
  }
}

// ---------- zero degree counters ----------
__global__ void zero_deg_kernel(int* __restrict__ deg) {
  int i = blockIdx.x * blockDim.x + threadIdx.x;
  if (i < N_NODES) deg[i] = 0;
}

// ---------- histogram of dst ----------
__global__ void hist_kernel(const int* __restrict__ ei, int* __restrict__ deg) {
  int e = blockIdx.x * blockDim.x + threadIdx.x;
  if (e < N_EDGES) atomicAdd(&deg[clampi(ei[N_EDGES + e])], 1);
}

// ---------- single-block exclusive scan over 50000 degrees ----------
__global__ __launch_bounds__(1024) void scan_kernel(const int* __restrict__ deg,
                                                    int* __restrict__ offsets,
                                                    int* __restrict__ cursor) {
  __shared__ int wsum[16];
  __shared__ int sbase;
  int t = threadIdx.x, lane = t & 63, wid = t >> 6;
  if (t == 0) sbase = 0;
  __syncthreads();
  for (int base = 0; base < N_NODES; base += 1024) {
    int i = base + t;
    int v = (i < N_NODES) ? deg[i] : 0;
    int s = v;
#pragma unroll
    for (int d = 1; d < 64; d <<= 1) {
      int u = __shfl_up(s, d);
      if (lane >= d) s += u;
    }
    if (lane == 63) wsum[wid] = s;
    __syncthreads();
    if (wid == 0 && lane < 16) {
      int ws = wsum[lane];
#pragma unroll
      for (int d = 1; d < 16; d <<= 1) {
        int u = __shfl_up(ws, d);
        if (lane >= d) ws += u;
      }
      wsum[lane] = ws;
    }
    __syncthreads();
    int wprev = (wid == 0) ? 0 : wsum[wid - 1];
    int excl = sbase + wprev + s - v;
    if (i < N_NODES) { offsets[i] = excl; cursor[i] = excl; }
    __syncthreads();
    if (t == 1023) sbase = sbase + wprev + s;
    __syncthreads();
  }
  if (t == 0) offsets[N_NODES] = sbase;
}

// ---------- reorder: perm[sorted_slot] = original edge id ----------
__global__ void reorder_kernel(const int* __restrict__ ei, int* __restrict__ cursor,
                               int* __restrict__ perm) {
  int e = blockIdx.x * blockDim.x + threadIdx.x;
  if (e < N_EDGES) {
    int d = clampi(ei[N_EDGES + e]);
    int p = atomicAdd(&cursor[d], 1);
    perm[p] = e;
  }
}

// ---------- transpose weights to bf16, n-major ----------
__global__ void prep_weights_kernel(const float* __restrict__ W, const float* __restrict__ W1,
                                    u16* __restrict__ wt, u16* __restrict__ w1t) {
  int t = blockIdx.x * blockDim.x + threadIdx.x;
  if (t < 128 * 128) {
    int k = t >> 7, n = t & 127;
    wt[n * 128 + k] = f2bf(W[k * 128 + n]);
  } else {
    int t2 = t - 128 * 128;
    int k = t2 >> 7, n = t2 & 127;
    w1t[n * 256 + k] = f2bf(W1[k * 128 + n]);
  }
}

// ---------- x_t = x @ W + b  (bf16 MFMA from xb, bf16 out to ws) ----------
#define WTP 136
__global__ __launch_bounds__(256) void xform_kernel(
    const u16* __restrict__ xb, const u16* __restrict__ wt,
    const float* __restrict__ bias, u16* __restrict__ xt)
{
  __shared__ u16 wl[128 * WTP];
  for (int c = threadIdx.x; c < 128 * 16; c += 256) {
    int nrow = c >> 4, ko = (c & 15) * 8;
    *(bf16x8*)&wl[nrow * WTP + ko] = *(const bf16x8*)(wt + nrow * 128 + ko);
  }
  __syncthreads();
  int w = threadIdx.x >> 6, l = threadIdx.x & 63;
  int r2 = l & 15, q = l >> 4;
  int rowbase = blockIdx.x * 128 + w * 32;
  float bv[8];
#pragma unroll
  for (int nf = 0; nf < 8; nf++) bv[nf] = bias[r2 + 16 * nf];
  int ra0 = rowbase + r2;       if (ra0 >= N_NODES) ra0 = N_NODES - 1;
  int ra1 = rowbase + 16 + r2;  if (ra1 >= N_NODES) ra1 = N_NODES - 1;
  const u16* pa0 = xb + ra0 * F + q * 8;
  const u16* pa1 = xb + ra1 * F + q * 8;
  f32x4 acc0[8] = {}, acc1[8] = {};
#pragma unroll
  for (int k = 0; k < 4; k++) {
    bf16x8 a0 = *(const bf16x8*)(pa0 + 32 * k);
    bf16x8 a1 = *(const bf16x8*)(pa1 + 32 * k);
#pragma unroll
    for (int nf = 0; nf < 8; nf++) {
      bf16x8 b = *(const bf16x8*)&wl[(16 * nf + r2) * WTP + q * 8 + 32 * k];
      acc0[nf] = __builtin_amdgcn_mfma_f32_16x16x32_bf16(a0, b, acc0[nf], 0, 0, 0);
      acc1[nf] = __builtin_amdgcn_mfma_f32_16x16x32_bf16(a1, b, acc1[nf], 0, 0, 0);
    }
  }
#pragma unroll
  for (int nf = 0; nf < 8; nf++) {
#pragma unroll
    for (int r = 0; r < 4; r++) {
      int row0 = rowbase + 4 * q + r;
      int row1 = row0 + 16;
      int c = r2 + 16 * nf;
      if (row0 < N_NODES) xt[row0 * F + c] = f2bf(acc0[nf][r] + bv[nf]);
      if (row1 < N_NODES) xt[row1 * F + c] = f2bf(acc1[nf][r] + bv[nf]);
    }
  }
}

// ---------- gate kernel: 4 waves, 32 edges/wave, bf16 gathers ----------
#define TILE_EDGES 128
__global__ __launch_bounds__(256) void gate_kernel(
    const u16* __restrict__ xb, const u16* __restrict__ w1t,
    const float* __restrict__ b1, const float* __restrict__ w2f,
    const float* __restrict__ b2, const int* __restrict__ ei,
    float* __restrict__ ew)
{
  __shared__ u16 w1l[128 * 256];
  for (int c = threadIdx.x; c < 128 * 32; c += 256) {
    int nrow = c >> 5, slot = c & 31;
    *(bf16x8*)&w1l[nrow * 256 + ((slot ^ (nrow & 7)) << 3)] =
        *(const bf16x8*)(w1t + nrow * 256 + (slot << 3));
  }
  __syncthreads();
  int w = threadIdx.x >> 6, l = threadIdx.x & 63;
  int r2 = l & 15, q = l >> 4;
  int sw = r2 & 7;
  float b1v[8], w2v[8];
#pragma unroll
  for (int nf = 0; nf < 8; nf++) {
    b1v[nf] = b1[r2 + 16 * nf];
    w2v[nf] = w2f[r2 + 16 * nf];
  }
  float bias2 = b2[0];
  const int ntiles = N_EDGES / TILE_EDGES;
  for (int tile = blockIdx.x; tile < ntiles; tile += gridDim.x) {
    int ebase = tile * TILE_EDGES + w * 32;
    int s0 = clampi(ei[ebase + r2]);
    int d0 = clampi(ei[N_EDGES + ebase + r2]);
    int s1 = clampi(ei[ebase + 16 + r2]);
    int d1 = clampi(ei[N_EDGES + ebase + 16 + r2]);
    const u16* ps0 = xb + s0 * F + q * 8;
    const u16* pd0 = xb + d0 * F + q * 8;
    const u16* ps1 = xb + s1 * F + q * 8;
    const u16* pd1 = xb + d1 * F + q * 8;
    f32x4 acc0[8] = {}, acc1[8] = {};
#pragma unroll
    for (int k = 0; k < 8; k++) {
      const u16* pa0 = (k < 4) ? (ps0 + 32 * k) : (pd0 + 32 * (k - 4));
      const u16* pa1 = (k < 4) ? (ps1 + 32 * k) : (pd1 + 32 * (k - 4));
      bf16x8 a0 = *(const bf16x8*)pa0;
      bf16x8 a1 = *(const bf16x8*)pa1;
#pragma unroll
      for (int nf = 0; nf < 8; nf++) {
        bf16x8 b = *(const bf16x8*)&w1l[(16 * nf + r2) * 256 + (((q + 4 * k) ^ sw) << 3)];
        acc0[nf] = __builtin_amdgcn_mfma_f32_16x16x32_bf16(a0, b, acc0[nf], 0, 0, 0);
        acc1[nf] = __builtin_amdgcn_mfma_f32_16x16x32_bf16(a1, b, acc1[nf], 0, 0, 0);
      }
    }
    float t0[4], t1[4];
#pragma unroll
    for (int r = 0; r < 4; r++) {
      float sa = 0.f, sb = 0.f;
#pragma unroll
      for (int nf = 0; nf < 8; nf++) {
        float h0 = acc0[nf][r] + b1v[nf]; h0 = h0 > 0.f ? h0 : 0.f;
        float h1 = acc1[nf][r] + b1v[nf]; h1 = h1 > 0.f ? h1 : 0.f;
        sa += h0 * w2v[nf]; sb += h1 * w2v[nf];
      }
#pragma unroll
      for (int d = 1; d < 16; d <<= 1) {
        sa += __shfl_xor(sa, d);
        sb += __shfl_xor(sb, d);
      }
      t0[r] = sa; t1[r] = sb;
    }
    // one gate per edge; lanes with (r2&4)==0 own the 32 edges of this wave
    int rr = r2 & 3;
    int e = 4 * q + rr + ((r2 & 8) ? 16 : 0);
    float z0 = rr == 0 ? t0[0] : rr == 1 ? t0[1] : rr == 2 ? t0[2] : t0[3];
    float z1 = rr == 0 ? t1[0] : rr == 1 ? t1[1] : rr == 2 ? t1[2] : t1[3];
    float z = (r2 & 8) ? z1 : z0;
    if ((r2 & 4) == 0)
      ew[ebase + e] = 1.0f / (1.0f + __expf(-(z + bias2)));
  }
}

// ---------- aggregation: one wave per dst node, no atomics, unroll 4 ----------
__global__ __launch_bounds__(256) void aggregate_kernel(
    const u16* __restrict__ xt, const int* __restrict__ offsets,
    const int* __restrict__ perm, const int* __restrict__ ei,
    const float* __restrict__ ew, float* __restrict__ out)
{
  int n = (blockIdx.x * blockDim.x + threadIdx.x) >> 6;
  int lane = threadIdx.x & 63;
  if (n >= N_NODES) return;
  int p = offsets[n], end = offsets[n + 1];
  float a0 = 0.f, a1 = 0.f;
  for (; p + 3 < end; p += 4) {
    int e0 = perm[p], e1 = perm[p + 1], e2 = perm[p + 2], e3 = perm[p + 3];
    int s0 = clampi(ei[e0]), s1 = clampi(ei[e1]);
    int s2 = clampi(ei[e2]), s3 = clampi(ei[e3]);
    float w0 = ew[e0], w1 = ew[e1], w2 = ew[e2], w3 = ew[e3];
    unsigned v0 = *(const unsigned*)(xt + s0 * F + 2 * lane);
    unsigned v1 = *(const unsigned*)(xt + s1 * F + 2 * lane);
    unsigned v2 = *(const unsigned*)(xt + s2 * F + 2 * lane);
    unsigned v3 = *(const unsigned*)(xt + s3 * F + 2 * lane);
    a0 += w0 * __uint_as_float(v0 << 16) + w1 * __uint_as_float(v1 << 16)
        + w2 * __uint_as_float(v2 << 16) + w3 * __uint_as_float(v3 << 16);
    a1 += w0 * __uint_as_float(v0 & 0xffff0000u) + w1 * __uint_as_float(v1 & 0xffff0000u)
        + w2 * __uint_as_float(v2 & 0xffff0000u) + w3 * __uint_as_float(v3 & 0xffff0000u);
  }
  for (; p < end; p++) {
    int e0 = perm[p];
    int s0 = clampi(ei[e0]);
    float w0 = ew[e0];
    unsigned v0 = *(const unsigned*)(xt + s0 * F + 2 * lane);
    a0 += w0 * __uint_as_float(v0 << 16);
    a1 += w0 * __uint_as_float(v0 & 0xffff0000u);
  }
  out[n * F + 2 * lane] = a0;
  out[n * F + 2 * lane + 1] = a1;
}

extern "C" void kernel_launch(void* const* d_in, const int* in_sizes, int n_in,
                              void* d_out, int out_size, void* d_ws, size_t ws_size,
                              hipStream_t stream) {
  const float* x  = (const float*)d_in[0];
  const int* ei   = (const int*)d_in[1];   // int64 in reference -> int32 in harness
  const float* W  = (const float*)d_in[2];
  const float* b  = (const float*)d_in[3];
  const float* W1 = (const float*)d_in[4];
  const float* b1 = (const float*)d_in[5];
  const float* W2 = (const float*)d_in[6];
  const float* b2 = (const float*)d_in[7];
  float* out = (float*)d_out;

  // bf16 copy of x lives in d_out's first 12.8 MB until aggregate overwrites it
  u16* xb = (u16*)d_out;

  char* ws = (char*)d_ws;
  u16* xt      = (u16*)ws;                    // 12,800,000 B
  u16* wt      = (u16*)(ws + 12800000);       //     32,768 B
  u16* w1t     = (u16*)(ws + 12832768);       //     65,536 B
  int* offsets = (int*)(ws + 12898304);       //    200,004 B
  int* deg     = (int*)(ws + 13098308);       //    200,000 B
  int* cursor  = (int*)(ws + 13298308);       //    200,000 B
  int* perm    = (int*)(ws + 13498308);       //  3,200,000 B
  float* ewbuf = (float*)(ws + 16698308);     //  3,200,000 B  (total ~19.9 MB)

  convert_x_kernel<<<1024, 256, 0, stream>>>(x, xb);
  zero_deg_kernel<<<(N_NODES + 255) / 256, 256, 0, stream>>>(deg);
  prep_weights_kernel<<<192, 256, 0, stream>>>(W, W1, wt, w1t);
  hist_kernel<<<(N_EDGES + 255) / 256, 256, 0, stream>>>(ei, deg);
  scan_kernel<<<1, 1024, 0, stream>>>(deg, offsets, cursor);
  reorder_kernel<<<(N_EDGES + 255) / 256, 256, 0, stream>>>(ei, cursor, perm);
  xform_kernel<<<391, 256, 0, stream>>>(xb, wt, b, xt);
  gate_kernel<<<512, 256, 0, stream>>>(xb, w1t, b1, W2, b2, ei, ewbuf);
  aggregate_kernel<<<(N_NODES * 64 + 255) / 256, 256, 0, stream>>>(xt, offsets, perm, ei, ewbuf, out);
}

// Round 7
// 330.502 us; speedup vs baseline: 2.1498x; 1.1284x over previous
//
#include <hip/hip_runtime.h>

#define N_NODES 50000
#define N_EDGES 800000
#define F 128
#define K2 256

typedef unsigned short u16;
typedef __bf16 bf16x8 __attribute__((ext_vector_type(8)));
typedef float f32x4 __attribute__((ext_vector_type(4)));

__device__ inline u16 f2bf(float f) {
  union { float f; unsigned u; } v; v.f = f;
  unsigned r = v.u + 0x7fffu + ((v.u >> 16) & 1u);
  return (u16)(r >> 16);
}

__device__ inline int clampi(int v) {
  v = v < 0 ? 0 : v;
  return v >= N_NODES ? N_NODES - 1 : v;
}

// ---------- convert x (fp32) -> bf16 (staged in d_out's first 12.8 MB) ----------
__global__ void convert_x_kernel(const float* __restrict__ x, u16* __restrict__ xb) {
  int stride = gridDim.x * blockDim.x;
  int n = (N_NODES * F) / 8;
  for (int i = blockIdx.x * blockDim.x + threadIdx.x; i < n; i += stride) {
    const float4* px = (const float4*)x + 2 * i;
    float4 a = px[0], b = px[1];
    unsigned u0 = f2bf(a.x) | ((unsigned)f2bf(a.y) << 16);
    unsigned u1 = f2bf(a.z) | ((unsigned)f2bf(a.w) << 16);
    unsigned u2 = f2bf(b.x) | ((unsigned)f2bf(b.y) << 16);
    unsigned u3 = f2bf(b.z) | ((unsigned)f2bf(b.w) << 16);
    uint4 o; o.x = u0; o.y = u1; o.z = u2; o.w = u3;
    ((uint4*)xb)[i] = o;
  }
}

// ---------- zero degree counters ----------
__global__ void zero_deg_kernel(int* __restrict__ deg) {
  int i = blockIdx.x * blockDim.x + threadIdx.x;
  if (i < N_NODES) deg[i] = 0;
}

// ---------- histogram of dst ----------
__global__ void hist_kernel(const int* __restrict__ ei, int* __restrict__ deg) {
  int e = blockIdx.x * blockDim.x + threadIdx.x;
  if (e < N_EDGES) atomicAdd(&deg[clampi(ei[N_EDGES + e])], 1);
}

// ---------- single-block exclusive scan over 50000 degrees ----------
__global__ __launch_bounds__(1024) void scan_kernel(const int* __restrict__ deg,
                                                    int* __restrict__ offsets,
                                                    int* __restrict__ cursor) {
  __shared__ int wsum[16];
  __shared__ int sbase;
  int t = threadIdx.x, lane = t & 63, wid = t >> 6;
  if (t == 0) sbase = 0;
  __syncthreads();
  for (int base = 0; base < N_NODES; base += 1024) {
    int i = base + t;
    int v = (i < N_NODES) ? deg[i] : 0;
    int s = v;
#pragma unroll
    for (int d = 1; d < 64; d <<= 1) {
      int u = __shfl_up(s, d);
      if (lane >= d) s += u;
    }
    if (lane == 63) wsum[wid] = s;
    __syncthreads();
    if (wid == 0 && lane < 16) {
      int ws = wsum[lane];
#pragma unroll
      for (int d = 1; d < 16; d <<= 1) {
        int u = __shfl_up(ws, d);
        if (lane >= d) ws += u;
      }
      wsum[lane] = ws;
    }
    __syncthreads();
    int wprev = (wid == 0) ? 0 : wsum[wid - 1];
    int excl = sbase + wprev + s - v;
    if (i < N_NODES) { offsets[i] = excl; cursor[i] = excl; }
    __syncthreads();
    if (t == 1023) sbase = sbase + wprev + s;
    __syncthreads();
  }
  if (t == 0) offsets[N_NODES] = sbase;
}

// ---------- reorder: materialize dst-sorted endpoint arrays ----------
__global__ void reorder_kernel(const int* __restrict__ ei, int* __restrict__ cursor,
                               int* __restrict__ srcs, int* __restrict__ dsts) {
  int e = blockIdx.x * blockDim.x + threadIdx.x;
  if (e < N_EDGES) {
    int s = clampi(ei[e]);
    int d = clampi(ei[N_EDGES + e]);
    int p = atomicAdd(&cursor[d], 1);
    srcs[p] = s;
    dsts[p] = d;
  }
}

// ---------- transpose weights to bf16, n-major ----------
__global__ void prep_weights_kernel(const float* __restrict__ W, const float* __restrict__ W1,
                                    u16* __restrict__ wt, u16* __restrict__ w1t) {
  int t = blockIdx.x * blockDim.x + threadIdx.x;
  if (t < 128 * 128) {
    int k = t >> 7, n = t & 127;
    wt[n * 128 + k] = f2bf(W[k * 128 + n]);
  } else {
    int t2 = t - 128 * 128;
    int k = t2 >> 7, n = t2 & 127;
    w1t[n * 256 + k] = f2bf(W1[k * 128 + n]);
  }
}

// ---------- x_t = x @ W + b  (bf16 MFMA from xb, bf16 out to ws) ----------
#define WTP 136
__global__ __launch_bounds__(256) void xform_kernel(
    const u16* __restrict__ xb, const u16* __restrict__ wt,
    const float* __restrict__ bias, u16* __restrict__ xt)
{
  __shared__ u16 wl[128 * WTP];
  for (int c = threadIdx.x; c < 128 * 16; c += 256) {
    int nrow = c >> 4, ko = (c & 15) * 8;
    *(bf16x8*)&wl[nrow * WTP + ko] = *(const bf16x8*)(wt + nrow * 128 + ko);
  }
  __syncthreads();
  int w = threadIdx.x >> 6, l = threadIdx.x & 63;
  int r2 = l & 15, q = l >> 4;
  int rowbase = blockIdx.x * 128 + w * 32;
  float bv[8];
#pragma unroll
  for (int nf = 0; nf < 8; nf++) bv[nf] = bias[r2 + 16 * nf];
  int ra0 = rowbase + r2;       if (ra0 >= N_NODES) ra0 = N_NODES - 1;
  int ra1 = rowbase + 16 + r2;  if (ra1 >= N_NODES) ra1 = N_NODES - 1;
  const u16* pa0 = xb + ra0 * F + q * 8;
  const u16* pa1 = xb + ra1 * F + q * 8;
  f32x4 acc0[8] = {}, acc1[8] = {};
#pragma unroll
  for (int k = 0; k < 4; k++) {
    bf16x8 a0 = *(const bf16x8*)(pa0 + 32 * k);
    bf16x8 a1 = *(const bf16x8*)(pa1 + 32 * k);
#pragma unroll
    for (int nf = 0; nf < 8; nf++) {
      bf16x8 b = *(const bf16x8*)&wl[(16 * nf + r2) * WTP + q * 8 + 32 * k];
      acc0[nf] = __builtin_amdgcn_mfma_f32_16x16x32_bf16(a0, b, acc0[nf], 0, 0, 0);
      acc1[nf] = __builtin_amdgcn_mfma_f32_16x16x32_bf16(a1, b, acc1[nf], 0, 0, 0);
    }
  }
#pragma unroll
  for (int nf = 0; nf < 8; nf++) {
#pragma unroll
    for (int r = 0; r < 4; r++) {
      int row0 = rowbase + 4 * q + r;
      int row1 = row0 + 16;
      int c = r2 + 16 * nf;
      if (row0 < N_NODES) xt[row0 * F + c] = f2bf(acc0[nf][r] + bv[nf]);
      if (row1 < N_NODES) xt[row1 * F + c] = f2bf(acc1[nf][r] + bv[nf]);
    }
  }
}

// ---------- gate kernel: dst-sorted slots, 4 waves, 32 edges/wave ----------
#define TILE_EDGES 128
__global__ __launch_bounds__(256) void gate_kernel(
    const u16* __restrict__ xb, const u16* __restrict__ w1t,
    const float* __restrict__ b1, const float* __restrict__ w2f,
    const float* __restrict__ b2,
    const int* __restrict__ srcs, const int* __restrict__ dsts,
    float* __restrict__ ew)
{
  __shared__ u16 w1l[128 * 256];
  for (int c = threadIdx.x; c < 128 * 32; c += 256) {
    int nrow = c >> 5, slot = c & 31;
    *(bf16x8*)&w1l[nrow * 256 + ((slot ^ (nrow & 7)) << 3)] =
        *(const bf16x8*)(w1t + nrow * 256 + (slot << 3));
  }
  __syncthreads();
  int w = threadIdx.x >> 6, l = threadIdx.x & 63;
  int r2 = l & 15, q = l >> 4;
  int sw = r2 & 7;
  float b1v[8], w2v[8];
#pragma unroll
  for (int nf = 0; nf < 8; nf++) {
    b1v[nf] = b1[r2 + 16 * nf];
    w2v[nf] = w2f[r2 + 16 * nf];
  }
  float bias2 = b2[0];
  const int ntiles = N_EDGES / TILE_EDGES;
  for (int tile = blockIdx.x; tile < ntiles; tile += gridDim.x) {
    int ebase = tile * TILE_EDGES + w * 32;
    int s0 = srcs[ebase + r2];
    int d0 = dsts[ebase + r2];
    int s1 = srcs[ebase + 16 + r2];
    int d1 = dsts[ebase + 16 + r2];
    const u16* ps0 = xb + s0 * F + q * 8;
    const u16* pd0 = xb + d0 * F + q * 8;
    const u16* ps1 = xb + s1 * F + q * 8;
    const u16* pd1 = xb + d1 * F + q * 8;
    f32x4 acc0[8] = {}, acc1[8] = {};
#pragma unroll
    for (int k = 0; k < 8; k++) {
      const u16* pa0 = (k < 4) ? (ps0 + 32 * k) : (pd0 + 32 * (k - 4));
      const u16* pa1 = (k < 4) ? (ps1 + 32 * k) : (pd1 + 32 * (k - 4));
      bf16x8 a0 = *(const bf16x8*)pa0;
      bf16x8 a1 = *(const bf16x8*)pa1;
#pragma unroll
      for (int nf = 0; nf < 8; nf++) {
        bf16x8 b = *(const bf16x8*)&w1l[(16 * nf + r2) * 256 + (((q + 4 * k) ^ sw) << 3)];
        acc0[nf] = __builtin_amdgcn_mfma_f32_16x16x32_bf16(a0, b, acc0[nf], 0, 0, 0);
        acc1[nf] = __builtin_amdgcn_mfma_f32_16x16x32_bf16(a1, b, acc1[nf], 0, 0, 0);
      }
    }
    float t0[4], t1[4];
#pragma unroll
    for (int r = 0; r < 4; r++) {
      float sa = 0.f, sb = 0.f;
#pragma unroll
      for (int nf = 0; nf < 8; nf++) {
        float h0 = acc0[nf][r] + b1v[nf]; h0 = h0 > 0.f ? h0 : 0.f;
        float h1 = acc1[nf][r] + b1v[nf]; h1 = h1 > 0.f ? h1 : 0.f;
        sa += h0 * w2v[nf]; sb += h1 * w2v[nf];
      }
#pragma unroll
      for (int d = 1; d < 16; d <<= 1) {
        sa += __shfl_xor(sa, d);
        sb += __shfl_xor(sb, d);
      }
      t0[r] = sa; t1[r] = sb;
    }
    int rr = r2 & 3;
    int e = 4 * q + rr + ((r2 & 8) ? 16 : 0);
    float z0 = rr == 0 ? t0[0] : rr == 1 ? t0[1] : rr == 2 ? t0[2] : t0[3];
    float z1 = rr == 0 ? t1[0] : rr == 1 ? t1[1] : rr == 2 ? t1[2] : t1[3];
    float z = (r2 & 8) ? z1 : z0;
    if ((r2 & 4) == 0)
      ew[ebase + e] = 1.0f / (1.0f + __expf(-(z + bias2)));
  }
}

// ---------- aggregation: one wave per dst node; sequential srcs/ew ----------
__global__ __launch_bounds__(256) void aggregate_kernel(
    const u16* __restrict__ xt, const int* __restrict__ offsets,
    const int* __restrict__ srcs, const float* __restrict__ ew,
    float* __restrict__ out)
{
  int n = (blockIdx.x * blockDim.x + threadIdx.x) >> 6;
  int lane = threadIdx.x & 63;
  if (n >= N_NODES) return;
  int p = offsets[n], end = offsets[n + 1];
  float a0 = 0.f, a1 = 0.f;
  for (; p + 3 < end; p += 4) {
    int s0 = srcs[p], s1 = srcs[p + 1], s2 = srcs[p + 2], s3 = srcs[p + 3];
    float w0 = ew[p], w1 = ew[p + 1], w2 = ew[p + 2], w3 = ew[p + 3];
    unsigned v0 = *(const unsigned*)(xt + s0 * F + 2 * lane);
    unsigned v1 = *(const unsigned*)(xt + s1 * F + 2 * lane);
    unsigned v2 = *(const unsigned*)(xt + s2 * F + 2 * lane);
    unsigned v3 = *(const unsigned*)(xt + s3 * F + 2 * lane);
    a0 += w0 * __uint_as_float(v0 << 16) + w1 * __uint_as_float(v1 << 16)
        + w2 * __uint_as_float(v2 << 16) + w3 * __uint_as_float(v3 << 16);
    a1 += w0 * __uint_as_float(v0 & 0xffff0000u) + w1 * __uint_as_float(v1 & 0xffff0000u)
        + w2 * __uint_as_float(v2 & 0xffff0000u) + w3 * __uint_as_float(v3 & 0xffff0000u);
  }
  for (; p < end; p++) {
    int s0 = srcs[p];
    float w0 = ew[p];
    unsigned v0 = *(const unsigned*)(xt + s0 * F + 2 * lane);
    a0 += w0 * __uint_as_float(v0 << 16);
    a1 += w0 * __uint_as_float(v0 & 0xffff0000u);
  }
  out[n * F + 2 * lane] = a0;
  out[n * F + 2 * lane + 1] = a1;
}

extern "C" void kernel_launch(void* const* d_in, const int* in_sizes, int n_in,
                              void* d_out, int out_size, void* d_ws, size_t ws_size,
                              hipStream_t stream) {
  const float* x  = (const float*)d_in[0];
  const int* ei   = (const int*)d_in[1];   // int64 in reference -> int32 in harness
  const float* W  = (const float*)d_in[2];
  const float* b  = (const float*)d_in[3];
  const float* W1 = (const float*)d_in[4];
  const float* b1 = (const float*)d_in[5];
  const float* W2 = (const float*)d_in[6];
  const float* b2 = (const float*)d_in[7];
  float* out = (float*)d_out;

  // d_out scratch use (dead until aggregate writes):
  //   [0        .. 12.8MB) : xb  (bf16 copy of x)
  //   [12.8MB   .. 16.0MB) : dsts (dst-sorted dst ids)
  u16* xb  = (u16*)d_out;
  int* dsts = (int*)((char*)d_out + 12800000);

  char* ws = (char*)d_ws;
  u16* xt      = (u16*)ws;                    // 12,800,000 B
  u16* wt      = (u16*)(ws + 12800000);       //     32,768 B
  u16* w1t     = (u16*)(ws + 12832768);       //     65,536 B
  int* offsets = (int*)(ws + 12898304);       //    200,004 B
  int* deg     = (int*)(ws + 13098308);       //    200,000 B
  int* cursor  = (int*)(ws + 13298308);       //    200,000 B
  int* srcs    = (int*)(ws + 13498308);       //  3,200,000 B
  float* ewbuf = (float*)(ws + 16698308);     //  3,200,000 B  (total ~19.9 MB)

  convert_x_kernel<<<1024, 256, 0, stream>>>(x, xb);
  zero_deg_kernel<<<(N_NODES + 255) / 256, 256, 0, stream>>>(deg);
  prep_weights_kernel<<<192, 256, 0, stream>>>(W, W1, wt, w1t);
  hist_kernel<<<(N_EDGES + 255) / 256, 256, 0, stream>>>(ei, deg);
  scan_kernel<<<1, 1024, 0, stream>>>(deg, offsets, cursor);
  reorder_kernel<<<(N_EDGES + 255) / 256, 256, 0, stream>>>(ei, cursor, srcs, dsts);
  xform_kernel<<<391, 256, 0, stream>>>(xb, wt, b, xt);
  gate_kernel<<<512, 256, 0, stream>>>(xb, w1t, b1, W2, b2, srcs, dsts, ewbuf);
  aggregate_kernel<<<(N_NODES * 64 + 255) / 256, 256, 0, stream>>>(xt, offsets, srcs, ewbuf, out);
}

// Round 8
// 321.324 us; speedup vs baseline: 2.2112x; 1.0286x over previous
//
#include <hip/hip_runtime.h>

#define N_NODES 50000
#define N_EDGES 800000
#define F 128
#define K2 256

typedef unsigned short u16;
typedef __bf16 bf16x8 __attribute__((ext_vector_type(8)));
typedef float f32x4 __attribute__((ext_vector_type(4)));

__device__ inline u16 f2bf(float f) {
  union { float f; unsigned u; } v; v.f = f;
  unsigned r = v.u + 0x7fffu + ((v.u >> 16) & 1u);
  return (u16)(r >> 16);
}

__device__ inline int clampi(int v) {
  v = v < 0 ? 0 : v;
  return v >= N_NODES ? N_NODES - 1 : v;
}

// ---------- convert x (fp32) -> bf16 (staged in d_out's first 12.8 MB) ----------
__global__ void convert_x_kernel(const float* __restrict__ x, u16* __restrict__ xb) {
  int stride = gridDim.x * blockDim.x;
  int n = (N_NODES * F) / 8;
  for (int i = blockIdx.x * blockDim.x + threadIdx.x; i < n; i += stride) {
    const float4* px = (const float4*)x + 2 * i;
    float4 a = px[0], b = px[1];
    unsigned u0 = f2bf(a.x) | ((unsigned)f2bf(a.y) << 16);
    unsigned u1 = f2bf(a.z) | ((unsigned)f2bf(a.w) << 16);
    unsigned u2 = f2bf(b.x) | ((unsigned)f2bf(b.y) << 16);
    unsigned u3 = f2bf(b.z) | ((unsigned)f2bf(b.w) << 16);
    uint4 o; o.x = u0; o.y = u1; o.z = u2; o.w = u3;
    ((uint4*)xb)[i] = o;
  }
}

// ---------- zero degree counters ----------
__global__ void zero_deg_kernel(int* __restrict__ deg) {
  int i = blockIdx.x * blockDim.x + threadIdx.x;
  if (i < N_NODES) deg[i] = 0;
}

// ---------- histogram of dst ----------
__global__ void hist_kernel(const int* __restrict__ ei, int* __restrict__ deg) {
  int e = blockIdx.x * blockDim.x + threadIdx.x;
  if (e < N_EDGES) atomicAdd(&deg[clampi(ei[N_EDGES + e])], 1);
}

// ---------- single-block exclusive scan over 50000 degrees ----------
__global__ __launch_bounds__(1024) void scan_kernel(const int* __restrict__ deg,
                                                    int* __restrict__ offsets,
                                                    int* __restrict__ cursor) {
  __shared__ int wsum[16];
  __shared__ int sbase;
  int t = threadIdx.x, lane = t & 63, wid = t >> 6;
  if (t == 0) sbase = 0;
  __syncthreads();
  for (int base = 0; base < N_NODES; base += 1024) {
    int i = base + t;
    int v = (i < N_NODES) ? deg[i] : 0;
    int s = v;
#pragma unroll
    for (int d = 1; d < 64; d <<= 1) {
      int u = __shfl_up(s, d);
      if (lane >= d) s += u;
    }
    if (lane == 63) wsum[wid] = s;
    __syncthreads();
    if (wid == 0 && lane < 16) {
      int ws = wsum[lane];
#pragma unroll
      for (int d = 1; d < 16; d <<= 1) {
        int u = __shfl_up(ws, d);
        if (lane >= d) ws += u;
      }
      wsum[lane] = ws;
    }
    __syncthreads();
    int wprev = (wid == 0) ? 0 : wsum[wid - 1];
    int excl = sbase + wprev + s - v;
    if (i < N_NODES) { offsets[i] = excl; cursor[i] = excl; }
    __syncthreads();
    if (t == 1023) sbase = sbase + wprev + s;
    __syncthreads();
  }
  if (t == 0) offsets[N_NODES] = sbase;
}

// ---------- reorder: materialize dst-sorted endpoint arrays ----------
__global__ void reorder_kernel(const int* __restrict__ ei, int* __restrict__ cursor,
                               int* __restrict__ srcs, int* __restrict__ dsts) {
  int e = blockIdx.x * blockDim.x + threadIdx.x;
  if (e < N_EDGES) {
    int s = clampi(ei[e]);
    int d = clampi(ei[N_EDGES + e]);
    int p = atomicAdd(&cursor[d], 1);
    srcs[p] = s;
    dsts[p] = d;
  }
}

// ---------- transpose weights to bf16, n-major ----------
__global__ void prep_weights_kernel(const float* __restrict__ W, const float* __restrict__ W1,
                                    u16* __restrict__ wt, u16* __restrict__ w1t) {
  int t = blockIdx.x * blockDim.x + threadIdx.x;
  if (t < 128 * 128) {
    int k = t >> 7, n = t & 127;
    wt[n * 128 + k] = f2bf(W[k * 128 + n]);
  } else {
    int t2 = t - 128 * 128;
    int k = t2 >> 7, n = t2 & 127;
    w1t[n * 256 + k] = f2bf(W1[k * 128 + n]);
  }
}

// ---------- x_t = x @ W + b  (bf16 MFMA from xb, bf16 out to ws) ----------
#define WTP 136
__global__ __launch_bounds__(256) void xform_kernel(
    const u16* __restrict__ xb, const u16* __restrict__ wt,
    const float* __restrict__ bias, u16* __restrict__ xt)
{
  __shared__ u16 wl[128 * WTP];
  for (int c = threadIdx.x; c < 128 * 16; c += 256) {
    int nrow = c >> 4, ko = (c & 15) * 8;
    *(bf16x8*)&wl[nrow * WTP + ko] = *(const bf16x8*)(wt + nrow * 128 + ko);
  }
  __syncthreads();
  int w = threadIdx.x >> 6, l = threadIdx.x & 63;
  int r2 = l & 15, q = l >> 4;
  int rowbase = blockIdx.x * 128 + w * 32;
  float bv[8];
#pragma unroll
  for (int nf = 0; nf < 8; nf++) bv[nf] = bias[r2 + 16 * nf];
  int ra0 = rowbase + r2;       if (ra0 >= N_NODES) ra0 = N_NODES - 1;
  int ra1 = rowbase + 16 + r2;  if (ra1 >= N_NODES) ra1 = N_NODES - 1;
  const u16* pa0 = xb + ra0 * F + q * 8;
  const u16* pa1 = xb + ra1 * F + q * 8;
  f32x4 acc0[8] = {}, acc1[8] = {};
#pragma unroll
  for (int k = 0; k < 4; k++) {
    bf16x8 a0 = *(const bf16x8*)(pa0 + 32 * k);
    bf16x8 a1 = *(const bf16x8*)(pa1 + 32 * k);
#pragma unroll
    for (int nf = 0; nf < 8; nf++) {
      bf16x8 b = *(const bf16x8*)&wl[(16 * nf + r2) * WTP + q * 8 + 32 * k];
      acc0[nf] = __builtin_amdgcn_mfma_f32_16x16x32_bf16(a0, b, acc0[nf], 0, 0, 0);
      acc1[nf] = __builtin_amdgcn_mfma_f32_16x16x32_bf16(a1, b, acc1[nf], 0, 0, 0);
    }
  }
#pragma unroll
  for (int nf = 0; nf < 8; nf++) {
#pragma unroll
    for (int r = 0; r < 4; r++) {
      int row0 = rowbase + 4 * q + r;
      int row1 = row0 + 16;
      int c = r2 + 16 * nf;
      if (row0 < N_NODES) xt[row0 * F + c] = f2bf(acc0[nf][r] + bv[nf]);
      if (row1 < N_NODES) xt[row1 * F + c] = f2bf(acc1[nf][r] + bv[nf]);
    }
  }
}

// ---------- gate kernel: batch A-gathers, prefetch next indices ----------
#define TILE_EDGES 128
__global__ __launch_bounds__(256) void gate_kernel(
    const u16* __restrict__ xb, const u16* __restrict__ w1t,
    const float* __restrict__ b1, const float* __restrict__ w2f,
    const float* __restrict__ b2,
    const int* __restrict__ srcs, const int* __restrict__ dsts,
    float* __restrict__ ew)
{
  __shared__ u16 w1l[128 * 256];
  for (int c = threadIdx.x; c < 128 * 32; c += 256) {
    int nrow = c >> 5, slot = c & 31;
    *(bf16x8*)&w1l[nrow * 256 + ((slot ^ (nrow & 7)) << 3)] =
        *(const bf16x8*)(w1t + nrow * 256 + (slot << 3));
  }
  __syncthreads();
  int w = threadIdx.x >> 6, l = threadIdx.x & 63;
  int r2 = l & 15, q = l >> 4;
  int sw = r2 & 7;
  float b1v[8], w2v[8];
#pragma unroll
  for (int nf = 0; nf < 8; nf++) {
    b1v[nf] = b1[r2 + 16 * nf];
    w2v[nf] = w2f[r2 + 16 * nf];
  }
  float bias2 = b2[0];
  const int ntiles = N_EDGES / TILE_EDGES;
  int tile = blockIdx.x;
  if (tile >= ntiles) return;
  // preload first tile's indices
  int ebase0 = tile * TILE_EDGES + w * 32;
  int s0 = srcs[ebase0 + r2];
  int d0 = dsts[ebase0 + r2];
  int s1 = srcs[ebase0 + 16 + r2];
  int d1 = dsts[ebase0 + 16 + r2];
  for (; tile < ntiles; tile += gridDim.x) {
    int curbase = tile * TILE_EDGES + w * 32;
    const u16* ps0 = xb + s0 * F + q * 8;
    const u16* pd0 = xb + d0 * F + q * 8;
    const u16* ps1 = xb + s1 * F + q * 8;
    const u16* pd1 = xb + d1 * F + q * 8;
    // batch-issue all 16 A-fragment gathers (one latency exposure per tile)
    bf16x8 A0[8], A1[8];
#pragma unroll
    for (int k = 0; k < 4; k++) {
      A0[k]     = *(const bf16x8*)(ps0 + 32 * k);
      A0[k + 4] = *(const bf16x8*)(pd0 + 32 * k);
      A1[k]     = *(const bf16x8*)(ps1 + 32 * k);
      A1[k + 4] = *(const bf16x8*)(pd1 + 32 * k);
    }
    // prefetch next tile's indices under the MFMA chain
    int nt = tile + gridDim.x;
    int nbase = (nt < ntiles) ? (nt * TILE_EDGES + w * 32) : curbase;
    s0 = srcs[nbase + r2];
    d0 = dsts[nbase + r2];
    s1 = srcs[nbase + 16 + r2];
    d1 = dsts[nbase + 16 + r2];
    f32x4 acc0[8] = {}, acc1[8] = {};
#pragma unroll
    for (int k = 0; k < 8; k++) {
#pragma unroll
      for (int nf = 0; nf < 8; nf++) {
        bf16x8 b = *(const bf16x8*)&w1l[(16 * nf + r2) * 256 + (((q + 4 * k) ^ sw) << 3)];
        acc0[nf] = __builtin_amdgcn_mfma_f32_16x16x32_bf16(A0[k], b, acc0[nf], 0, 0, 0);
        acc1[nf] = __builtin_amdgcn_mfma_f32_16x16x32_bf16(A1[k], b, acc1[nf], 0, 0, 0);
      }
    }
    float t0[4], t1[4];
#pragma unroll
    for (int r = 0; r < 4; r++) {
      float sa = 0.f, sb = 0.f;
#pragma unroll
      for (int nf = 0; nf < 8; nf++) {
        float h0 = acc0[nf][r] + b1v[nf]; h0 = h0 > 0.f ? h0 : 0.f;
        float h1 = acc1[nf][r] + b1v[nf]; h1 = h1 > 0.f ? h1 : 0.f;
        sa += h0 * w2v[nf]; sb += h1 * w2v[nf];
      }
#pragma unroll
      for (int d = 1; d < 16; d <<= 1) {
        sa += __shfl_xor(sa, d);
        sb += __shfl_xor(sb, d);
      }
      t0[r] = sa; t1[r] = sb;
    }
    int rr = r2 & 3;
    int e = 4 * q + rr + ((r2 & 8) ? 16 : 0);
    float z0 = rr == 0 ? t0[0] : rr == 1 ? t0[1] : rr == 2 ? t0[2] : t0[3];
    float z1 = rr == 0 ? t1[0] : rr == 1 ? t1[1] : rr == 2 ? t1[2] : t1[3];
    float z = (r2 & 8) ? z1 : z0;
    if ((r2 & 4) == 0)
      ew[curbase + e] = 1.0f / (1.0f + __expf(-(z + bias2)));
  }
}

// ---------- aggregation: one wave per dst node; sequential srcs/ew; unroll 8 ----------
__global__ __launch_bounds__(256) void aggregate_kernel(
    const u16* __restrict__ xt, const int* __restrict__ offsets,
    const int* __restrict__ srcs, const float* __restrict__ ew,
    float* __restrict__ out)
{
  int n = (blockIdx.x * blockDim.x + threadIdx.x) >> 6;
  int lane = threadIdx.x & 63;
  if (n >= N_NODES) return;
  int p = offsets[n], end = offsets[n + 1];
  float a0 = 0.f, a1 = 0.f;
  for (; p + 7 < end; p += 8) {
    int s[8]; float w[8]; unsigned v[8];
#pragma unroll
    for (int i = 0; i < 8; i++) { s[i] = srcs[p + i]; w[i] = ew[p + i]; }
#pragma unroll
    for (int i = 0; i < 8; i++) v[i] = *(const unsigned*)(xt + s[i] * F + 2 * lane);
#pragma unroll
    for (int i = 0; i < 8; i++) {
      a0 += w[i] * __uint_as_float(v[i] << 16);
      a1 += w[i] * __uint_as_float(v[i] & 0xffff0000u);
    }
  }
  for (; p + 3 < end; p += 4) {
    int s0 = srcs[p], s1 = srcs[p + 1], s2 = srcs[p + 2], s3 = srcs[p + 3];
    float w0 = ew[p], w1 = ew[p + 1], w2 = ew[p + 2], w3 = ew[p + 3];
    unsigned v0 = *(const unsigned*)(xt + s0 * F + 2 * lane);
    unsigned v1 = *(const unsigned*)(xt + s1 * F + 2 * lane);
    unsigned v2 = *(const unsigned*)(xt + s2 * F + 2 * lane);
    unsigned v3 = *(const unsigned*)(xt + s3 * F + 2 * lane);
    a0 += w0 * __uint_as_float(v0 << 16) + w1 * __uint_as_float(v1 << 16)
        + w2 * __uint_as_float(v2 << 16) + w3 * __uint_as_float(v3 << 16);
    a1 += w0 * __uint_as_float(v0 & 0xffff0000u) + w1 * __uint_as_float(v1 & 0xffff0000u)
        + w2 * __uint_as_float(v2 & 0xffff0000u) + w3 * __uint_as_float(v3 & 0xffff0000u);
  }
  for (; p < end; p++) {
    int s0 = srcs[p];
    float w0 = ew[p];
    unsigned v0 = *(const unsigned*)(xt + s0 * F + 2 * lane);
    a0 += w0 * __uint_as_float(v0 << 16);
    a1 += w0 * __uint_as_float(v0 & 0xffff0000u);
  }
  out[n * F + 2 * lane] = a0;
  out[n * F + 2 * lane + 1] = a1;
}

extern "C" void kernel_launch(void* const* d_in, const int* in_sizes, int n_in,
                              void* d_out, int out_size, void* d_ws, size_t ws_size,
                              hipStream_t stream) {
  const float* x  = (const float*)d_in[0];
  const int* ei   = (const int*)d_in[1];   // int64 in reference -> int32 in harness
  const float* W  = (const float*)d_in[2];
  const float* b  = (const float*)d_in[3];
  const float* W1 = (const float*)d_in[4];
  const float* b1 = (const float*)d_in[5];
  const float* W2 = (const float*)d_in[6];
  const float* b2 = (const float*)d_in[7];
  float* out = (float*)d_out;

  // d_out scratch use (dead until aggregate writes):
  //   [0      .. 12.8MB) : xb   (bf16 copy of x)
  //   [12.8MB .. 16.0MB) : dsts (dst-sorted dst ids)
  u16* xb   = (u16*)d_out;
  int* dsts = (int*)((char*)d_out + 12800000);

  char* ws = (char*)d_ws;
  u16* xt      = (u16*)ws;                    // 12,800,000 B
  u16* wt      = (u16*)(ws + 12800000);       //     32,768 B
  u16* w1t     = (u16*)(ws + 12832768);       //     65,536 B
  int* offsets = (int*)(ws + 12898304);       //    200,004 B
  int* deg     = (int*)(ws + 13098308);       //    200,000 B
  int* cursor  = (int*)(ws + 13298308);       //    200,000 B
  int* srcs    = (int*)(ws + 13498308);       //  3,200,000 B
  float* ewbuf = (float*)(ws + 16698308);     //  3,200,000 B  (total ~19.9 MB)

  convert_x_kernel<<<1024, 256, 0, stream>>>(x, xb);
  zero_deg_kernel<<<(N_NODES + 255) / 256, 256, 0, stream>>>(deg);
  prep_weights_kernel<<<192, 256, 0, stream>>>(W, W1, wt, w1t);
  hist_kernel<<<(N_EDGES + 255) / 256, 256, 0, stream>>>(ei, deg);
  scan_kernel<<<1, 1024, 0, stream>>>(deg, offsets, cursor);
  reorder_kernel<<<(N_EDGES + 255) / 256, 256, 0, stream>>>(ei, cursor, srcs, dsts);
  xform_kernel<<<391, 256, 0, stream>>>(xb, wt, b, xt);
  gate_kernel<<<512, 256, 0, stream>>>(xb, w1t, b1, W2, b2, srcs, dsts, ewbuf);
  aggregate_kernel<<<(N_NODES * 64 + 255) / 256, 256, 0, stream>>>(xt, offsets, srcs, ewbuf, out);
}

// Round 9
// 235.225 us; speedup vs baseline: 3.0206x; 1.3660x over previous
//
#include <hip/hip_runtime.h>

#define N_NODES 50000
#define N_EDGES 800000
#define F 128

typedef unsigned short u16;
typedef __bf16 bf16x8 __attribute__((ext_vector_type(8)));
typedef float f32x4 __attribute__((ext_vector_type(4)));

__device__ inline u16 f2bf(float f) {
  union { float f; unsigned u; } v; v.f = f;
  unsigned r = v.u + 0x7fffu + ((v.u >> 16) & 1u);
  return (u16)(r >> 16);
}

__device__ inline int clampi(int v) {
  v = v < 0 ? 0 : v;
  return v >= N_NODES ? N_NODES - 1 : v;
}

// ---------- convert x (fp32) -> bf16 (staged in d_out's first 12.8 MB) ----------
__global__ void convert_x_kernel(const float* __restrict__ x, u16* __restrict__ xb) {
  int stride = gridDim.x * blockDim.x;
  int n = (N_NODES * F) / 8;
  for (int i = blockIdx.x * blockDim.x + threadIdx.x; i < n; i += stride) {
    const float4* px = (const float4*)x + 2 * i;
    float4 a = px[0], b = px[1];
    unsigned u0 = f2bf(a.x) | ((unsigned)f2bf(a.y) << 16);
    unsigned u1 = f2bf(a.z) | ((unsigned)f2bf(a.w) << 16);
    unsigned u2 = f2bf(b.x) | ((unsigned)f2bf(b.y) << 16);
    unsigned u3 = f2bf(b.z) | ((unsigned)f2bf(b.w) << 16);
    uint4 o; o.x = u0; o.y = u1; o.z = u2; o.w = u3;
    ((uint4*)xb)[i] = o;
  }
}

// ---------- zero degree counters ----------
__global__ void zero_deg_kernel(int* __restrict__ deg) {
  int i = blockIdx.x * blockDim.x + threadIdx.x;
  if (i < N_NODES) deg[i] = 0;
}

// ---------- histogram of dst ----------
__global__ void hist_kernel(const int* __restrict__ ei, int* __restrict__ deg) {
  int e = blockIdx.x * blockDim.x + threadIdx.x;
  if (e < N_EDGES) atomicAdd(&deg[clampi(ei[N_EDGES + e])], 1);
}

// ---------- single-block exclusive scan over 50000 degrees ----------
__global__ __launch_bounds__(1024) void scan_kernel(const int* __restrict__ deg,
                                                    int* __restrict__ offsets,
                                                    int* __restrict__ cursor) {
  __shared__ int wsum[16];
  __shared__ int sbase;
  int t = threadIdx.x, lane = t & 63, wid = t >> 6;
  if (t == 0) sbase = 0;
  __syncthreads();
  for (int base = 0; base < N_NODES; base += 1024) {
    int i = base + t;
    int v = (i < N_NODES) ? deg[i] : 0;
    int s = v;
#pragma unroll
    for (int d = 1; d < 64; d <<= 1) {
      int u = __shfl_up(s, d);
      if (lane >= d) s += u;
    }
    if (lane == 63) wsum[wid] = s;
    __syncthreads();
    if (wid == 0 && lane < 16) {
      int ws = wsum[lane];
#pragma unroll
      for (int d = 1; d < 16; d <<= 1) {
        int u = __shfl_up(ws, d);
        if (lane >= d) ws += u;
      }
      wsum[lane] = ws;
    }
    __syncthreads();
    int wprev = (wid == 0) ? 0 : wsum[wid - 1];
    int excl = sbase + wprev + s - v;
    if (i < N_NODES) { offsets[i] = excl; cursor[i] = excl; }
    __syncthreads();
    if (t == 1023) sbase = sbase + wprev + s;
    __syncthreads();
  }
  if (t == 0) offsets[N_NODES] = sbase;
}

// ---------- reorder: srcs[p] = src of p-th dst-sorted edge (pre-clamped) ----------
__global__ void reorder_kernel(const int* __restrict__ ei, int* __restrict__ cursor,
                               int* __restrict__ srcs) {
  int e = blockIdx.x * blockDim.x + threadIdx.x;
  if (e < N_EDGES) {
    int s = clampi(ei[e]);
    int d = clampi(ei[N_EDGES + e]);
    int p = atomicAdd(&cursor[d], 1);
    srcs[p] = s;
  }
}

// ---------- weights: wt[n][k]=W[k][n]; w1t2[n][k]=W1s^T (n<128) / W1d^T (n>=128) ----------
__global__ void prep_weights_kernel(const float* __restrict__ W, const float* __restrict__ W1,
                                    u16* __restrict__ wt, u16* __restrict__ w1t2) {
  int t = blockIdx.x * blockDim.x + threadIdx.x;
  if (t < 128 * 128) {
    int k = t >> 7, n = t & 127;
    wt[n * 128 + k] = f2bf(W[k * 128 + n]);
  } else {
    int t2 = t - 128 * 128;           // 0 .. 32767
    int n2 = t2 >> 7, k = t2 & 127;   // n2: 0..255
    float v = (n2 < 128) ? W1[k * 128 + n2] : W1[(128 + k) * 128 + (n2 - 128)];
    w1t2[n2 * 128 + k] = f2bf(v);
  }
}

// ---------- x_t = x @ W + b  -> uxt[.][128:256] (bf16) ----------
#define WTP 136
__global__ __launch_bounds__(256) void xform_kernel(
    const u16* __restrict__ xb, const u16* __restrict__ wt,
    const float* __restrict__ bias, u16* __restrict__ uxt)
{
  __shared__ u16 wl[128 * WTP];
  for (int c = threadIdx.x; c < 128 * 16; c += 256) {
    int nrow = c >> 4, ko = (c & 15) * 8;
    *(bf16x8*)&wl[nrow * WTP + ko] = *(const bf16x8*)(wt + nrow * 128 + ko);
  }
  __syncthreads();
  int w = threadIdx.x >> 6, l = threadIdx.x & 63;
  int r2 = l & 15, q = l >> 4;
  int rowbase = blockIdx.x * 128 + w * 32;
  float bv[8];
#pragma unroll
  for (int nf = 0; nf < 8; nf++) bv[nf] = bias[r2 + 16 * nf];
  int ra0 = rowbase + r2;       if (ra0 >= N_NODES) ra0 = N_NODES - 1;
  int ra1 = rowbase + 16 + r2;  if (ra1 >= N_NODES) ra1 = N_NODES - 1;
  const u16* pa0 = xb + ra0 * F + q * 8;
  const u16* pa1 = xb + ra1 * F + q * 8;
  f32x4 acc0[8] = {}, acc1[8] = {};
#pragma unroll
  for (int k = 0; k < 4; k++) {
    bf16x8 a0 = *(const bf16x8*)(pa0 + 32 * k);
    bf16x8 a1 = *(const bf16x8*)(pa1 + 32 * k);
#pragma unroll
    for (int nf = 0; nf < 8; nf++) {
      bf16x8 b = *(const bf16x8*)&wl[(16 * nf + r2) * WTP + q * 8 + 32 * k];
      acc0[nf] = __builtin_amdgcn_mfma_f32_16x16x32_bf16(a0, b, acc0[nf], 0, 0, 0);
      acc1[nf] = __builtin_amdgcn_mfma_f32_16x16x32_bf16(a1, b, acc1[nf], 0, 0, 0);
    }
  }
#pragma unroll
  for (int nf = 0; nf < 8; nf++) {
#pragma unroll
    for (int r = 0; r < 4; r++) {
      int row0 = rowbase + 4 * q + r;
      int row1 = row0 + 16;
      int c = r2 + 16 * nf;
      if (row0 < N_NODES) uxt[row0 * 256 + 128 + c] = f2bf(acc0[nf][r] + bv[nf]);
      if (row1 < N_NODES) uxt[row1 * 256 + 128 + c] = f2bf(acc1[nf][r] + bv[nf]);
    }
  }
}

// ---------- u = x@W1s -> uxt[.][0:128]; v = x@W1d + b1 -> vout ----------
__global__ __launch_bounds__(256) void uv_kernel(
    const u16* __restrict__ xb, const u16* __restrict__ w1t2,
    const float* __restrict__ b1,
    u16* __restrict__ uxt, u16* __restrict__ vout)
{
  __shared__ u16 wl[256 * 128];  // 64KB, slot XOR-swizzled by (row&7)
  for (int c = threadIdx.x; c < 256 * 16; c += 256) {
    int row = c >> 4, slot = c & 15;
    *(bf16x8*)&wl[row * 128 + ((slot ^ (row & 7)) << 3)] =
        *(const bf16x8*)(w1t2 + row * 128 + slot * 8);
  }
  __syncthreads();
  int w = threadIdx.x >> 6, l = threadIdx.x & 63;
  int r2 = l & 15, q = l >> 4;
  int sw = r2 & 7;
  int rowbase = blockIdx.x * 128 + w * 32;
  int ra0 = rowbase + r2;       if (ra0 >= N_NODES) ra0 = N_NODES - 1;
  int ra1 = rowbase + 16 + r2;  if (ra1 >= N_NODES) ra1 = N_NODES - 1;
  bf16x8 A0[4], A1[4];
#pragma unroll
  for (int k = 0; k < 4; k++) {
    A0[k] = *(const bf16x8*)(xb + ra0 * F + q * 8 + 32 * k);
    A1[k] = *(const bf16x8*)(xb + ra1 * F + q * 8 + 32 * k);
  }
  // ---- phase u: rows 0..127 of w1t2, bias 0 ----
  {
    f32x4 acc0[8] = {}, acc1[8] = {};
#pragma unroll
    for (int k = 0; k < 4; k++) {
#pragma unroll
      for (int nf = 0; nf < 8; nf++) {
        bf16x8 b = *(const bf16x8*)&wl[(16 * nf + r2) * 128 + (((q + 4 * k) ^ sw) << 3)];
        acc0[nf] = __builtin_amdgcn_mfma_f32_16x16x32_bf16(A0[k], b, acc0[nf], 0, 0, 0);
        acc1[nf] = __builtin_amdgcn_mfma_f32_16x16x32_bf16(A1[k], b, acc1[nf], 0, 0, 0);
      }
    }
#pragma unroll
    for (int nf = 0; nf < 8; nf++) {
#pragma unroll
      for (int r = 0; r < 4; r++) {
        int row0 = rowbase + 4 * q + r;
        int row1 = row0 + 16;
        int c = r2 + 16 * nf;
        if (row0 < N_NODES) uxt[row0 * 256 + c] = f2bf(acc0[nf][r]);
        if (row1 < N_NODES) uxt[row1 * 256 + c] = f2bf(acc1[nf][r]);
      }
    }
  }
  // ---- phase v: rows 128..255 of w1t2, bias b1 ----
  {
    float b1v[8];
#pragma unroll
    for (int nf = 0; nf < 8; nf++) b1v[nf] = b1[r2 + 16 * nf];
    f32x4 acc0[8] = {}, acc1[8] = {};
#pragma unroll
    for (int k = 0; k < 4; k++) {
#pragma unroll
      for (int nf = 0; nf < 8; nf++) {
        bf16x8 b = *(const bf16x8*)&wl[(128 + 16 * nf + r2) * 128 + (((q + 4 * k) ^ sw) << 3)];
        acc0[nf] = __builtin_amdgcn_mfma_f32_16x16x32_bf16(A0[k], b, acc0[nf], 0, 0, 0);
        acc1[nf] = __builtin_amdgcn_mfma_f32_16x16x32_bf16(A1[k], b, acc1[nf], 0, 0, 0);
      }
    }
#pragma unroll
    for (int nf = 0; nf < 8; nf++) {
#pragma unroll
      for (int r = 0; r < 4; r++) {
        int row0 = rowbase + 4 * q + r;
        int row1 = row0 + 16;
        int c = r2 + 16 * nf;
        if (row0 < N_NODES) vout[row0 * F + c] = f2bf(acc0[nf][r] + b1v[nf]);
        if (row1 < N_NODES) vout[row1 * F + c] = f2bf(acc1[nf][r] + b1v[nf]);
      }
    }
  }
}

// ---------- fused gate + aggregate: one wave per dst node ----------
// gate_e = sigmoid(w2 . relu(u[src]+v[n]) + b2); out[n] = sum gate_e * xt[src]
__global__ __launch_bounds__(256) void edge_fused_kernel(
    const u16* __restrict__ uxt, const u16* __restrict__ v,
    const int* __restrict__ offsets, const int* __restrict__ srcs,
    const float* __restrict__ w2f, const float* __restrict__ b2,
    float* __restrict__ out)
{
  int n = (blockIdx.x * blockDim.x + threadIdx.x) >> 6;
  if (n >= N_NODES) return;
  int lane = threadIdx.x & 63;
  int g = lane >> 4, j = lane & 15;     // group g handles edge slot base+g; lane chunk = elems 8j..8j+7
  float w2v[8], vn[8];
  float4 wa = *(const float4*)(w2f + 8 * j);
  float4 wb = *(const float4*)(w2f + 8 * j + 4);
  w2v[0] = wa.x; w2v[1] = wa.y; w2v[2] = wa.z; w2v[3] = wa.w;
  w2v[4] = wb.x; w2v[5] = wb.y; w2v[6] = wb.z; w2v[7] = wb.w;
  bf16x8 vv = *(const bf16x8*)(v + n * F + 8 * j);
#pragma unroll
  for (int i = 0; i < 8; i++) vn[i] = (float)vv[i];
  float bias2 = b2[0];
  float acc[8] = {};
  int p = offsets[n], end = offsets[n + 1];
  for (int base = p; base < end; base += 4) {
    int slot = base + g;
    bool valid = slot < end;
    int sp = srcs[valid ? slot : end - 1];
    const u16* row = uxt + (size_t)sp * 256;
    bf16x8 uu = *(const bf16x8*)(row + 8 * j);          // u chunk
    bf16x8 xx = *(const bf16x8*)(row + 128 + 8 * j);    // xt chunk
    float t = 0.f;
#pragma unroll
    for (int i = 0; i < 8; i++) {
      float h = (float)uu[i] + vn[i];
      h = h > 0.f ? h : 0.f;
      t += h * w2v[i];
    }
    t += __shfl_xor(t, 1);
    t += __shfl_xor(t, 2);
    t += __shfl_xor(t, 4);
    t += __shfl_xor(t, 8);
    float gate = valid ? 1.0f / (1.0f + __expf(-(t + bias2))) : 0.f;
#pragma unroll
    for (int i = 0; i < 8; i++) acc[i] += gate * (float)xx[i];
  }
#pragma unroll
  for (int i = 0; i < 8; i++) acc[i] += __shfl_xor(acc[i], 16);
#pragma unroll
  for (int i = 0; i < 8; i++) acc[i] += __shfl_xor(acc[i], 32);
  if (g == 0) {
    float4 o0, o1;
    o0.x = acc[0]; o0.y = acc[1]; o0.z = acc[2]; o0.w = acc[3];
    o1.x = acc[4]; o1.y = acc[5]; o1.z = acc[6]; o1.w = acc[7];
    *(float4*)(out + n * F + 8 * j) = o0;
    *(float4*)(out + n * F + 8 * j + 4) = o1;
  }
}

extern "C" void kernel_launch(void* const* d_in, const int* in_sizes, int n_in,
                              void* d_out, int out_size, void* d_ws, size_t ws_size,
                              hipStream_t stream) {
  const float* x  = (const float*)d_in[0];
  const int* ei   = (const int*)d_in[1];   // int64 in reference -> int32 in harness
  const float* W  = (const float*)d_in[2];
  const float* b  = (const float*)d_in[3];
  const float* W1 = (const float*)d_in[4];
  const float* b1 = (const float*)d_in[5];
  const float* W2 = (const float*)d_in[6];
  const float* b2 = (const float*)d_in[7];
  float* out = (float*)d_out;

  // d_out[0:12.8MB] holds xb (bf16 x) until edge_fused overwrites out at the end;
  // xb is only read by xform/uv which complete before edge_fused starts.
  u16* xb = (u16*)d_out;

  char* ws = (char*)d_ws;
  u16* uxt     = (u16*)ws;                    // 25,600,000 B  [n][0:128]=u, [128:256]=xt
  u16* vout    = (u16*)(ws + 25600000);       // 12,800,000 B  v + b1
  u16* wt      = (u16*)(ws + 38400000);       //     32,768 B
  u16* w1t2    = (u16*)(ws + 38432768);       //     65,536 B
  int* offsets = (int*)(ws + 38498304);       //    200,004 B
  int* deg     = (int*)(ws + 38698308);       //    200,000 B
  int* cursor  = (int*)(ws + 38898308);       //    200,000 B
  int* srcs    = (int*)(ws + 39098308);       //  3,200,000 B   total 42,298,308 B
  float* dummy = nullptr; (void)dummy; (void)ws_size;

  convert_x_kernel<<<1024, 256, 0, stream>>>(x, xb);
  zero_deg_kernel<<<(N_NODES + 255) / 256, 256, 0, stream>>>(deg);
  prep_weights_kernel<<<192, 256, 0, stream>>>(W, W1, wt, w1t2);
  hist_kernel<<<(N_EDGES + 255) / 256, 256, 0, stream>>>(ei, deg);
  scan_kernel<<<1, 1024, 0, stream>>>(deg, offsets, cursor);
  reorder_kernel<<<(N_EDGES + 255) / 256, 256, 0, stream>>>(ei, cursor, srcs);
  xform_kernel<<<391, 256, 0, stream>>>(xb, wt, b, uxt);
  uv_kernel<<<391, 256, 0, stream>>>(xb, w1t2, b1, uxt, vout);
  edge_fused_kernel<<<(N_NODES * 64 + 255) / 256, 256, 0, stream>>>(
      uxt, vout, offsets, srcs, W2, b2, out);
}

// Round 10
// 228.753 us; speedup vs baseline: 3.1060x; 1.0283x over previous
//
#include <hip/hip_runtime.h>

#define N_NODES 50000
#define N_EDGES 800000
#define F 128

typedef unsigned short u16;
typedef __bf16 bf16x8 __attribute__((ext_vector_type(8)));
typedef float f32x4 __attribute__((ext_vector_type(4)));

__device__ inline u16 f2bf(float f) {
  union { float f; unsigned u; } v; v.f = f;
  unsigned r = v.u + 0x7fffu + ((v.u >> 16) & 1u);
  return (u16)(r >> 16);
}

__device__ inline int clampi(int v) {
  v = v < 0 ? 0 : v;
  return v >= N_NODES ? N_NODES - 1 : v;
}

// ---------- zero degree counters ----------
__global__ void zero_deg_kernel(int* __restrict__ deg) {
  int i = blockIdx.x * blockDim.x + threadIdx.x;
  if (i < N_NODES) deg[i] = 0;
}

// ---------- fused setup: convert x->bf16 | transpose weights | dst histogram ----------
#define CONV_BLOCKS 1024
#define PREP_BLOCKS 192
#define HIST_BLOCKS 832
__global__ __launch_bounds__(256) void setup_kernel(
    const float* __restrict__ x, u16* __restrict__ xb,
    const float* __restrict__ W, const float* __restrict__ W1,
    u16* __restrict__ wt, u16* __restrict__ w1t2,
    const int* __restrict__ ei, int* __restrict__ deg)
{
  int bid = blockIdx.x;
  if (bid < CONV_BLOCKS) {
    int stride = CONV_BLOCKS * 256;
    int n = (N_NODES * F) / 8;
    for (int i = bid * 256 + threadIdx.x; i < n; i += stride) {
      const float4* px = (const float4*)x + 2 * i;
      float4 a = px[0], b = px[1];
      unsigned u0 = f2bf(a.x) | ((unsigned)f2bf(a.y) << 16);
      unsigned u1 = f2bf(a.z) | ((unsigned)f2bf(a.w) << 16);
      unsigned u2 = f2bf(b.x) | ((unsigned)f2bf(b.y) << 16);
      unsigned u3 = f2bf(b.z) | ((unsigned)f2bf(b.w) << 16);
      uint4 o; o.x = u0; o.y = u1; o.z = u2; o.w = u3;
      ((uint4*)xb)[i] = o;
    }
  } else if (bid < CONV_BLOCKS + PREP_BLOCKS) {
    int t = (bid - CONV_BLOCKS) * 256 + threadIdx.x;  // 0 .. 49151
    if (t < 128 * 128) {
      int k = t >> 7, n = t & 127;
      wt[n * 128 + k] = f2bf(W[k * 128 + n]);
    } else {
      int t2 = t - 128 * 128;           // 0 .. 32767
      int n2 = t2 >> 7, k = t2 & 127;   // n2: 0..255
      float v = (n2 < 128) ? W1[k * 128 + n2] : W1[(128 + k) * 128 + (n2 - 128)];
      w1t2[n2 * 128 + k] = f2bf(v);
    }
  } else {
    int stride = HIST_BLOCKS * 256;
    for (int e = (bid - CONV_BLOCKS - PREP_BLOCKS) * 256 + threadIdx.x; e < N_EDGES; e += stride)
      atomicAdd(&deg[clampi(ei[N_EDGES + e])], 1);
  }
}

// ---------- single-block exclusive scan over 50000 degrees ----------
__global__ __launch_bounds__(1024) void scan_kernel(const int* __restrict__ deg,
                                                    int* __restrict__ offsets,
                                                    int* __restrict__ cursor) {
  __shared__ int wsum[16];
  __shared__ int sbase;
  int t = threadIdx.x, lane = t & 63, wid = t >> 6;
  if (t == 0) sbase = 0;
  __syncthreads();
  for (int base = 0; base < N_NODES; base += 1024) {
    int i = base + t;
    int v = (i < N_NODES) ? deg[i] : 0;
    int s = v;
#pragma unroll
    for (int d = 1; d < 64; d <<= 1) {
      int u = __shfl_up(s, d);
      if (lane >= d) s += u;
    }
    if (lane == 63) wsum[wid] = s;
    __syncthreads();
    if (wid == 0 && lane < 16) {
      int ws = wsum[lane];
#pragma unroll
      for (int d = 1; d < 16; d <<= 1) {
        int u = __shfl_up(ws, d);
        if (lane >= d) ws += u;
      }
      wsum[lane] = ws;
    }
    __syncthreads();
    int wprev = (wid == 0) ? 0 : wsum[wid - 1];
    int excl = sbase + wprev + s - v;
    if (i < N_NODES) { offsets[i] = excl; cursor[i] = excl; }
    __syncthreads();
    if (t == 1023) sbase = sbase + wprev + s;
    __syncthreads();
  }
  if (t == 0) offsets[N_NODES] = sbase;
}

// ---------- reorder: srcs[p] = src of p-th dst-sorted edge (pre-clamped) ----------
__global__ void reorder_kernel(const int* __restrict__ ei, int* __restrict__ cursor,
                               int* __restrict__ srcs) {
  int e = blockIdx.x * blockDim.x + threadIdx.x;
  if (e < N_EDGES) {
    int s = clampi(ei[e]);
    int d = clampi(ei[N_EDGES + e]);
    int p = atomicAdd(&cursor[d], 1);
    srcs[p] = s;
  }
}

// ---------- node GEMMs: xt = x@W+b, u = x@W1s, v = x@W1d+b1, one A-load ----------
__global__ __launch_bounds__(256) void node_gemm_kernel(
    const u16* __restrict__ xb, const u16* __restrict__ wt,
    const u16* __restrict__ w1t2, const float* __restrict__ bias,
    const float* __restrict__ b1,
    u16* __restrict__ uxt, u16* __restrict__ vout)
{
  __shared__ u16 wl[256 * 128];  // 64KB, slot XOR-swizzled by (row&7)
  int w = threadIdx.x >> 6, l = threadIdx.x & 63;
  int r2 = l & 15, q = l >> 4;
  int sw = r2 & 7;
  int rowbase = blockIdx.x * 128 + w * 32;
  int ra0 = rowbase + r2;       if (ra0 >= N_NODES) ra0 = N_NODES - 1;
  int ra1 = rowbase + 16 + r2;  if (ra1 >= N_NODES) ra1 = N_NODES - 1;
  // phase 1 LDS: wt (128 rows x 128) in first 32KB
  for (int c = threadIdx.x; c < 128 * 16; c += 256) {
    int row = c >> 4, slot = c & 15;
    *(bf16x8*)&wl[row * 128 + ((slot ^ (row & 7)) << 3)] =
        *(const bf16x8*)(wt + row * 128 + slot * 8);
  }
  // A-fragments: loaded once, used by all three GEMMs
  bf16x8 A0[4], A1[4];
#pragma unroll
  for (int k = 0; k < 4; k++) {
    A0[k] = *(const bf16x8*)(xb + ra0 * F + q * 8 + 32 * k);
    A1[k] = *(const bf16x8*)(xb + ra1 * F + q * 8 + 32 * k);
  }
  __syncthreads();
  // ---- phase 1: xt = x@W + b -> uxt[.][128:256] ----
  {
    float bv[8];
#pragma unroll
    for (int nf = 0; nf < 8; nf++) bv[nf] = bias[r2 + 16 * nf];
    f32x4 acc0[8] = {}, acc1[8] = {};
#pragma unroll
    for (int k = 0; k < 4; k++) {
#pragma unroll
      for (int nf = 0; nf < 8; nf++) {
        bf16x8 b = *(const bf16x8*)&wl[(16 * nf + r2) * 128 + (((q + 4 * k) ^ sw) << 3)];
        acc0[nf] = __builtin_amdgcn_mfma_f32_16x16x32_bf16(A0[k], b, acc0[nf], 0, 0, 0);
        acc1[nf] = __builtin_amdgcn_mfma_f32_16x16x32_bf16(A1[k], b, acc1[nf], 0, 0, 0);
      }
    }
#pragma unroll
    for (int nf = 0; nf < 8; nf++) {
#pragma unroll
      for (int r = 0; r < 4; r++) {
        int row0 = rowbase + 4 * q + r;
        int row1 = row0 + 16;
        int c = r2 + 16 * nf;
        if (row0 < N_NODES) uxt[row0 * 256 + 128 + c] = f2bf(acc0[nf][r] + bv[nf]);
        if (row1 < N_NODES) uxt[row1 * 256 + 128 + c] = f2bf(acc1[nf][r] + bv[nf]);
      }
    }
  }
  __syncthreads();
  // phase 2 LDS: w1t2 (256 rows x 128) fills all 64KB
  for (int c = threadIdx.x; c < 256 * 16; c += 256) {
    int row = c >> 4, slot = c & 15;
    *(bf16x8*)&wl[row * 128 + ((slot ^ (row & 7)) << 3)] =
        *(const bf16x8*)(w1t2 + row * 128 + slot * 8);
  }
  __syncthreads();
  // ---- phase 2a: u = x@W1s -> uxt[.][0:128] ----
  {
    f32x4 acc0[8] = {}, acc1[8] = {};
#pragma unroll
    for (int k = 0; k < 4; k++) {
#pragma unroll
      for (int nf = 0; nf < 8; nf++) {
        bf16x8 b = *(const bf16x8*)&wl[(16 * nf + r2) * 128 + (((q + 4 * k) ^ sw) << 3)];
        acc0[nf] = __builtin_amdgcn_mfma_f32_16x16x32_bf16(A0[k], b, acc0[nf], 0, 0, 0);
        acc1[nf] = __builtin_amdgcn_mfma_f32_16x16x32_bf16(A1[k], b, acc1[nf], 0, 0, 0);
      }
    }
#pragma unroll
    for (int nf = 0; nf < 8; nf++) {
#pragma unroll
      for (int r = 0; r < 4; r++) {
        int row0 = rowbase + 4 * q + r;
        int row1 = row0 + 16;
        int c = r2 + 16 * nf;
        if (row0 < N_NODES) uxt[row0 * 256 + c] = f2bf(acc0[nf][r]);
        if (row1 < N_NODES) uxt[row1 * 256 + c] = f2bf(acc1[nf][r]);
      }
    }
  }
  // ---- phase 2b: v = x@W1d + b1 -> vout ----
  {
    float b1v[8];
#pragma unroll
    for (int nf = 0; nf < 8; nf++) b1v[nf] = b1[r2 + 16 * nf];
    f32x4 acc0[8] = {}, acc1[8] = {};
#pragma unroll
    for (int k = 0; k < 4; k++) {
#pragma unroll
      for (int nf = 0; nf < 8; nf++) {
        bf16x8 b = *(const bf16x8*)&wl[(128 + 16 * nf + r2) * 128 + (((q + 4 * k) ^ sw) << 3)];
        acc0[nf] = __builtin_amdgcn_mfma_f32_16x16x32_bf16(A0[k], b, acc0[nf], 0, 0, 0);
        acc1[nf] = __builtin_amdgcn_mfma_f32_16x16x32_bf16(A1[k], b, acc1[nf], 0, 0, 0);
      }
    }
#pragma unroll
    for (int nf = 0; nf < 8; nf++) {
#pragma unroll
      for (int r = 0; r < 4; r++) {
        int row0 = rowbase + 4 * q + r;
        int row1 = row0 + 16;
        int c = r2 + 16 * nf;
        if (row0 < N_NODES) vout[row0 * F + c] = f2bf(acc0[nf][r] + b1v[nf]);
        if (row1 < N_NODES) vout[row1 * F + c] = f2bf(acc1[nf][r] + b1v[nf]);
      }
    }
  }
}

// ---------- fused gate + aggregate: one wave per dst node ----------
// gate_e = sigmoid(w2 . relu(u[src]+v[n]) + b2); out[n] = sum gate_e * xt[src]
__global__ __launch_bounds__(256) void edge_fused_kernel(
    const u16* __restrict__ uxt, const u16* __restrict__ v,
    const int* __restrict__ offsets, const int* __restrict__ srcs,
    const float* __restrict__ w2f, const float* __restrict__ b2,
    float* __restrict__ out)
{
  int n = (blockIdx.x * blockDim.x + threadIdx.x) >> 6;
  if (n >= N_NODES) return;
  int lane = threadIdx.x & 63;
  int g = lane >> 4, j = lane & 15;     // group g handles edge slot base+g; lane chunk = elems 8j..8j+7
  float w2v[8], vn[8];
  float4 wa = *(const float4*)(w2f + 8 * j);
  float4 wb = *(const float4*)(w2f + 8 * j + 4);
  w2v[0] = wa.x; w2v[1] = wa.y; w2v[2] = wa.z; w2v[3] = wa.w;
  w2v[4] = wb.x; w2v[5] = wb.y; w2v[6] = wb.z; w2v[7] = wb.w;
  bf16x8 vv = *(const bf16x8*)(v + n * F + 8 * j);
#pragma unroll
  for (int i = 0; i < 8; i++) vn[i] = (float)vv[i];
  float bias2 = b2[0];
  float acc[8] = {};
  int p = offsets[n], end = offsets[n + 1];
  for (int base = p; base < end; base += 4) {
    int slot = base + g;
    bool valid = slot < end;
    int sp = srcs[valid ? slot : end - 1];
    const u16* row = uxt + (size_t)sp * 256;
    bf16x8 uu = *(const bf16x8*)(row + 8 * j);          // u chunk
    bf16x8 xx = *(const bf16x8*)(row + 128 + 8 * j);    // xt chunk
    float t = 0.f;
#pragma unroll
    for (int i = 0; i < 8; i++) {
      float h = (float)uu[i] + vn[i];
      h = h > 0.f ? h : 0.f;
      t += h * w2v[i];
    }
    t += __shfl_xor(t, 1);
    t += __shfl_xor(t, 2);
    t += __shfl_xor(t, 4);
    t += __shfl_xor(t, 8);
    float gate = valid ? 1.0f / (1.0f + __expf(-(t + bias2))) : 0.f;
#pragma unroll
    for (int i = 0; i < 8; i++) acc[i] += gate * (float)xx[i];
  }
#pragma unroll
  for (int i = 0; i < 8; i++) acc[i] += __shfl_xor(acc[i], 16);
#pragma unroll
  for (int i = 0; i < 8; i++) acc[i] += __shfl_xor(acc[i], 32);
  if (g == 0) {
    float4 o0, o1;
    o0.x = acc[0]; o0.y = acc[1]; o0.z = acc[2]; o0.w = acc[3];
    o1.x = acc[4]; o1.y = acc[5]; o1.z = acc[6]; o1.w = acc[7];
    *(float4*)(out + n * F + 8 * j) = o0;
    *(float4*)(out + n * F + 8 * j + 4) = o1;
  }
}

extern "C" void kernel_launch(void* const* d_in, const int* in_sizes, int n_in,
                              void* d_out, int out_size, void* d_ws, size_t ws_size,
                              hipStream_t stream) {
  const float* x  = (const float*)d_in[0];
  const int* ei   = (const int*)d_in[1];   // int64 in reference -> int32 in harness
  const float* W  = (const float*)d_in[2];
  const float* b  = (const float*)d_in[3];
  const float* W1 = (const float*)d_in[4];
  const float* b1 = (const float*)d_in[5];
  const float* W2 = (const float*)d_in[6];
  const float* b2 = (const float*)d_in[7];
  float* out = (float*)d_out;

  // d_out[0:12.8MB] holds xb (bf16 x) until edge_fused overwrites out at the end;
  // xb is only read by node_gemm which completes before edge_fused starts.
  u16* xb = (u16*)d_out;

  char* ws = (char*)d_ws;
  u16* uxt     = (u16*)ws;                    // 25,600,000 B  [n][0:128]=u, [128:256]=xt
  u16* vout    = (u16*)(ws + 25600000);       // 12,800,000 B  v + b1
  u16* wt      = (u16*)(ws + 38400000);       //     32,768 B
  u16* w1t2    = (u16*)(ws + 38432768);       //     65,536 B
  int* offsets = (int*)(ws + 38498304);       //    200,004 B
  int* deg     = (int*)(ws + 38698308);       //    200,000 B
  int* cursor  = (int*)(ws + 38898308);       //    200,000 B
  int* srcs    = (int*)(ws + 39098308);       //  3,200,000 B   total 42,298,308 B
  (void)ws_size;

  zero_deg_kernel<<<(N_NODES + 255) / 256, 256, 0, stream>>>(deg);
  setup_kernel<<<CONV_BLOCKS + PREP_BLOCKS + HIST_BLOCKS, 256, 0, stream>>>(
      x, xb, W, W1, wt, w1t2, ei, deg);
  scan_kernel<<<1, 1024, 0, stream>>>(deg, offsets, cursor);
  reorder_kernel<<<(N_EDGES + 255) / 256, 256, 0, stream>>>(ei, cursor, srcs);
  node_gemm_kernel<<<391, 256, 0, stream>>>(xb, wt, w1t2, b, b1, uxt, vout);
  edge_fused_kernel<<<(N_NODES * 64 + 255) / 256, 256, 0, stream>>>(
      uxt, vout, offsets, srcs, W2, b2, out);
}

// Round 11
// 179.985 us; speedup vs baseline: 3.9476x; 1.2710x over previous
//
#include <hip/hip_runtime.h>

#define N_NODES 50000
#define N_EDGES 800000
#define F 128

typedef unsigned short u16;
typedef __bf16 bf16x8 __attribute__((ext_vector_type(8)));
typedef float f32x4 __attribute__((ext_vector_type(4)));

__device__ inline u16 f2bf(float f) {
  union { float f; unsigned u; } v; v.f = f;
  unsigned r = v.u + 0x7fffu + ((v.u >> 16) & 1u);
  return (u16)(r >> 16);
}

__device__ inline int clampi(int v) {
  v = v < 0 ? 0 : v;
  return v >= N_NODES ? N_NODES - 1 : v;
}

// ---------- zero degree counters ----------
__global__ void zero_deg_kernel(int* __restrict__ deg) {
  int i = blockIdx.x * blockDim.x + threadIdx.x;
  if (i < N_NODES) deg[i] = 0;
}

// ---------- fused setup: convert x->bf16 | transpose weights | dst histogram ----------
#define CONV_BLOCKS 1024
#define PREP_BLOCKS 192
#define HIST_BLOCKS 832
__global__ __launch_bounds__(256) void setup_kernel(
    const float* __restrict__ x, u16* __restrict__ xb,
    const float* __restrict__ W, const float* __restrict__ W1,
    u16* __restrict__ wt, u16* __restrict__ w1t2,
    const int* __restrict__ ei, int* __restrict__ deg)
{
  int bid = blockIdx.x;
  if (bid < CONV_BLOCKS) {
    int stride = CONV_BLOCKS * 256;
    int n = (N_NODES * F) / 8;
    for (int i = bid * 256 + threadIdx.x; i < n; i += stride) {
      const float4* px = (const float4*)x + 2 * i;
      float4 a = px[0], b = px[1];
      unsigned u0 = f2bf(a.x) | ((unsigned)f2bf(a.y) << 16);
      unsigned u1 = f2bf(a.z) | ((unsigned)f2bf(a.w) << 16);
      unsigned u2 = f2bf(b.x) | ((unsigned)f2bf(b.y) << 16);
      unsigned u3 = f2bf(b.z) | ((unsigned)f2bf(b.w) << 16);
      uint4 o; o.x = u0; o.y = u1; o.z = u2; o.w = u3;
      ((uint4*)xb)[i] = o;
    }
  } else if (bid < CONV_BLOCKS + PREP_BLOCKS) {
    int t = (bid - CONV_BLOCKS) * 256 + threadIdx.x;  // 0 .. 49151
    if (t < 128 * 128) {
      int k = t >> 7, n = t & 127;
      wt[n * 128 + k] = f2bf(W[k * 128 + n]);
    } else {
      int t2 = t - 128 * 128;           // 0 .. 32767
      int n2 = t2 >> 7, k = t2 & 127;   // n2: 0..255
      float v = (n2 < 128) ? W1[k * 128 + n2] : W1[(128 + k) * 128 + (n2 - 128)];
      w1t2[n2 * 128 + k] = f2bf(v);
    }
  } else {
    int stride = HIST_BLOCKS * 256;
    for (int e = (bid - CONV_BLOCKS - PREP_BLOCKS) * 256 + threadIdx.x; e < N_EDGES; e += stride)
      atomicAdd(&deg[clampi(ei[N_EDGES + e])], 1);
  }
}

// ---------- hierarchical scan: 49-block partial scan ----------
#define SCAN_BLOCKS 49
__global__ __launch_bounds__(1024) void scan1_kernel(const int* __restrict__ deg,
                                                     int* __restrict__ offsets,
                                                     int* __restrict__ bsum) {
  __shared__ int wsum[16];
  int t = threadIdx.x, lane = t & 63, wid = t >> 6;
  int i = blockIdx.x * 1024 + t;
  int v = (i < N_NODES) ? deg[i] : 0;
  int s = v;
#pragma unroll
  for (int d = 1; d < 64; d <<= 1) {
    int u = __shfl_up(s, d);
    if (lane >= d) s += u;
  }
  if (lane == 63) wsum[wid] = s;
  __syncthreads();
  if (wid == 0 && lane < 16) {
    int ws = wsum[lane];
#pragma unroll
    for (int d = 1; d < 16; d <<= 1) {
      int u = __shfl_up(ws, d);
      if (lane >= d) ws += u;
    }
    wsum[lane] = ws;  // inclusive per-wave totals
  }
  __syncthreads();
  int wprev = (wid == 0) ? 0 : wsum[wid - 1];
  if (i < N_NODES) offsets[i] = wprev + s - v;  // block-local exclusive
  if (t == 0) bsum[blockIdx.x] = wsum[15];      // block total
}

// ---------- scan of the 49 block sums (one wave) ----------
__global__ void scan2_kernel(const int* __restrict__ bsum, int* __restrict__ bbase,
                             int* __restrict__ offsets) {
  int t = threadIdx.x;  // 64 threads
  int v = (t < SCAN_BLOCKS) ? bsum[t] : 0;
  int s = v;
#pragma unroll
  for (int d = 1; d < 64; d <<= 1) {
    int u = __shfl_up(s, d);
    if (t >= d) s += u;
  }
  if (t < SCAN_BLOCKS) bbase[t] = s - v;        // exclusive base per block
  if (t == SCAN_BLOCKS - 1) offsets[N_NODES] = s;  // grand total
}

// ---------- add block base; fill cursor ----------
__global__ void scan3_kernel(int* __restrict__ offsets, const int* __restrict__ bbase,
                             int* __restrict__ cursor) {
  int i = blockIdx.x * blockDim.x + threadIdx.x;
  if (i < N_NODES) {
    int off = offsets[i] + bbase[i >> 10];
    offsets[i] = off;
    cursor[i] = off;
  }
}

// ---------- reorder: srcs[p] = src of p-th dst-sorted edge (pre-clamped) ----------
__global__ void reorder_kernel(const int* __restrict__ ei, int* __restrict__ cursor,
                               int* __restrict__ srcs) {
  int e = blockIdx.x * blockDim.x + threadIdx.x;
  if (e < N_EDGES) {
    int s = clampi(ei[e]);
    int d = clampi(ei[N_EDGES + e]);
    int p = atomicAdd(&cursor[d], 1);
    srcs[p] = s;
  }
}

// ---------- node GEMMs: 16 rows/wave, 64 rows/block, 3 x 32KB LDS phases ----------
__global__ __launch_bounds__(256) void node_gemm_kernel(
    const u16* __restrict__ xb, const u16* __restrict__ wt,
    const u16* __restrict__ w1t2, const float* __restrict__ bias,
    const float* __restrict__ b1,
    u16* __restrict__ uxt, u16* __restrict__ vout)
{
  __shared__ u16 wl[128 * 128];  // 32KB, slot XOR-swizzled by (row&7)
  int w = threadIdx.x >> 6, l = threadIdx.x & 63;
  int r2 = l & 15, q = l >> 4;
  int sw = r2 & 7;
  int rowbase = blockIdx.x * 64 + w * 16;
  int ra = rowbase + r2;  if (ra >= N_NODES) ra = N_NODES - 1;
  // A-fragments: loaded once, used by all three GEMMs
  bf16x8 A[4];
#pragma unroll
  for (int k = 0; k < 4; k++)
    A[k] = *(const bf16x8*)(xb + ra * F + q * 8 + 32 * k);

  // ---- phase 1: stage wt; xt = x@W + b -> uxt[.][128:256] ----
  for (int c = threadIdx.x; c < 128 * 16; c += 256) {
    int row = c >> 4, slot = c & 15;
    *(bf16x8*)&wl[row * 128 + ((slot ^ (row & 7)) << 3)] =
        *(const bf16x8*)(wt + row * 128 + slot * 8);
  }
  __syncthreads();
  {
    float bv[8];
#pragma unroll
    for (int nf = 0; nf < 8; nf++) bv[nf] = bias[r2 + 16 * nf];
    f32x4 acc[8] = {};
#pragma unroll
    for (int k = 0; k < 4; k++) {
#pragma unroll
      for (int nf = 0; nf < 8; nf++) {
        bf16x8 b = *(const bf16x8*)&wl[(16 * nf + r2) * 128 + (((q + 4 * k) ^ sw) << 3)];
        acc[nf] = __builtin_amdgcn_mfma_f32_16x16x32_bf16(A[k], b, acc[nf], 0, 0, 0);
      }
    }
#pragma unroll
    for (int nf = 0; nf < 8; nf++) {
#pragma unroll
      for (int r = 0; r < 4; r++) {
        int row = rowbase + 4 * q + r;
        int c = r2 + 16 * nf;
        if (row < N_NODES) uxt[row * 256 + 128 + c] = f2bf(acc[nf][r] + bv[nf]);
      }
    }
  }
  __syncthreads();
  // ---- phase 2: stage W1s; u = x@W1s -> uxt[.][0:128] ----
  for (int c = threadIdx.x; c < 128 * 16; c += 256) {
    int row = c >> 4, slot = c & 15;
    *(bf16x8*)&wl[row * 128 + ((slot ^ (row & 7)) << 3)] =
        *(const bf16x8*)(w1t2 + row * 128 + slot * 8);
  }
  __syncthreads();
  {
    f32x4 acc[8] = {};
#pragma unroll
    for (int k = 0; k < 4; k++) {
#pragma unroll
      for (int nf = 0; nf < 8; nf++) {
        bf16x8 b = *(const bf16x8*)&wl[(16 * nf + r2) * 128 + (((q + 4 * k) ^ sw) << 3)];
        acc[nf] = __builtin_amdgcn_mfma_f32_16x16x32_bf16(A[k], b, acc[nf], 0, 0, 0);
      }
    }
#pragma unroll
    for (int nf = 0; nf < 8; nf++) {
#pragma unroll
      for (int r = 0; r < 4; r++) {
        int row = rowbase + 4 * q + r;
        int c = r2 + 16 * nf;
        if (row < N_NODES) uxt[row * 256 + c] = f2bf(acc[nf][r]);
      }
    }
  }
  __syncthreads();
  // ---- phase 3: stage W1d; v = x@W1d + b1 -> vout ----
  for (int c = threadIdx.x; c < 128 * 16; c += 256) {
    int row = c >> 4, slot = c & 15;
    *(bf16x8*)&wl[row * 128 + ((slot ^ (row & 7)) << 3)] =
        *(const bf16x8*)(w1t2 + 128 * 128 + row * 128 + slot * 8);
  }
  __syncthreads();
  {
    float b1v[8];
#pragma unroll
    for (int nf = 0; nf < 8; nf++) b1v[nf] = b1[r2 + 16 * nf];
    f32x4 acc[8] = {};
#pragma unroll
    for (int k = 0; k < 4; k++) {
#pragma unroll
      for (int nf = 0; nf < 8; nf++) {
        bf16x8 b = *(const bf16x8*)&wl[(16 * nf + r2) * 128 + (((q + 4 * k) ^ sw) << 3)];
        acc[nf] = __builtin_amdgcn_mfma_f32_16x16x32_bf16(A[k], b, acc[nf], 0, 0, 0);
      }
    }
#pragma unroll
    for (int nf = 0; nf < 8; nf++) {
#pragma unroll
      for (int r = 0; r < 4; r++) {
        int row = rowbase + 4 * q + r;
        int c = r2 + 16 * nf;
        if (row < N_NODES) vout[row * F + c] = f2bf(acc[nf][r] + b1v[nf]);
      }
    }
  }
}

// ---------- fused gate + aggregate: one wave per dst node ----------
// gate_e = sigmoid(w2 . relu(u[src]+v[n]) + b2); out[n] = sum gate_e * xt[src]
__global__ __launch_bounds__(256) void edge_fused_kernel(
    const u16* __restrict__ uxt, const u16* __restrict__ v,
    const int* __restrict__ offsets, const int* __restrict__ srcs,
    const float* __restrict__ w2f, const float* __restrict__ b2,
    float* __restrict__ out)
{
  int n = (blockIdx.x * blockDim.x + threadIdx.x) >> 6;
  if (n >= N_NODES) return;
  int lane = threadIdx.x & 63;
  int g = lane >> 4, j = lane & 15;
  float w2v[8], vn[8];
  float4 wa = *(const float4*)(w2f + 8 * j);
  float4 wb = *(const float4*)(w2f + 8 * j + 4);
  w2v[0] = wa.x; w2v[1] = wa.y; w2v[2] = wa.z; w2v[3] = wa.w;
  w2v[4] = wb.x; w2v[5] = wb.y; w2v[6] = wb.z; w2v[7] = wb.w;
  bf16x8 vv = *(const bf16x8*)(v + n * F + 8 * j);
#pragma unroll
  for (int i = 0; i < 8; i++) vn[i] = (float)vv[i];
  float bias2 = b2[0];
  float acc[8] = {};
  int p = offsets[n], end = offsets[n + 1];
  for (int base = p; base < end; base += 4) {
    int slot = base + g;
    bool valid = slot < end;
    int sp = srcs[valid ? slot : end - 1];
    const u16* row = uxt + (size_t)sp * 256;
    bf16x8 uu = *(const bf16x8*)(row + 8 * j);
    bf16x8 xx = *(const bf16x8*)(row + 128 + 8 * j);
    float t = 0.f;
#pragma unroll
    for (int i = 0; i < 8; i++) {
      float h = (float)uu[i] + vn[i];
      h = h > 0.f ? h : 0.f;
      t += h * w2v[i];
    }
    t += __shfl_xor(t, 1);
    t += __shfl_xor(t, 2);
    t += __shfl_xor(t, 4);
    t += __shfl_xor(t, 8);
    float gate = valid ? 1.0f / (1.0f + __expf(-(t + bias2))) : 0.f;
#pragma unroll
    for (int i = 0; i < 8; i++) acc[i] += gate * (float)xx[i];
  }
#pragma unroll
  for (int i = 0; i < 8; i++) acc[i] += __shfl_xor(acc[i], 16);
#pragma unroll
  for (int i = 0; i < 8; i++) acc[i] += __shfl_xor(acc[i], 32);
  if (g == 0) {
    float4 o0, o1;
    o0.x = acc[0]; o0.y = acc[1]; o0.z = acc[2]; o0.w = acc[3];
    o1.x = acc[4]; o1.y = acc[5]; o1.z = acc[6]; o1.w = acc[7];
    *(float4*)(out + n * F + 8 * j) = o0;
    *(float4*)(out + n * F + 8 * j + 4) = o1;
  }
}

extern "C" void kernel_launch(void* const* d_in, const int* in_sizes, int n_in,
                              void* d_out, int out_size, void* d_ws, size_t ws_size,
                              hipStream_t stream) {
  const float* x  = (const float*)d_in[0];
  const int* ei   = (const int*)d_in[1];   // int64 in reference -> int32 in harness
  const float* W  = (const float*)d_in[2];
  const float* b  = (const float*)d_in[3];
  const float* W1 = (const float*)d_in[4];
  const float* b1 = (const float*)d_in[5];
  const float* W2 = (const float*)d_in[6];
  const float* b2 = (const float*)d_in[7];
  float* out = (float*)d_out;

  // d_out[0:12.8MB] holds xb (bf16 x) until edge_fused overwrites out at the end;
  // xb is only read by node_gemm which completes before edge_fused starts.
  u16* xb = (u16*)d_out;

  char* ws = (char*)d_ws;
  u16* uxt     = (u16*)ws;                    // 25,600,000 B  [n][0:128]=u, [128:256]=xt
  u16* vout    = (u16*)(ws + 25600000);       // 12,800,000 B  v + b1
  u16* wt      = (u16*)(ws + 38400000);       //     32,768 B
  u16* w1t2    = (u16*)(ws + 38432768);       //     65,536 B
  int* offsets = (int*)(ws + 38498304);       //    200,004 B
  int* deg     = (int*)(ws + 38698308);       //    200,000 B
  int* cursor  = (int*)(ws + 38898308);       //    200,000 B
  int* srcs    = (int*)(ws + 39098308);       //  3,200,000 B
  int* bsum    = (int*)(ws + 42298308);       //        196 B
  int* bbase   = (int*)(ws + 42298504);       //        196 B   total ~42.3 MB
  (void)ws_size;

  zero_deg_kernel<<<(N_NODES + 255) / 256, 256, 0, stream>>>(deg);
  setup_kernel<<<CONV_BLOCKS + PREP_BLOCKS + HIST_BLOCKS, 256, 0, stream>>>(
      x, xb, W, W1, wt, w1t2, ei, deg);
  scan1_kernel<<<SCAN_BLOCKS, 1024, 0, stream>>>(deg, offsets, bsum);
  scan2_kernel<<<1, 64, 0, stream>>>(bsum, bbase, offsets);
  scan3_kernel<<<(N_NODES + 255) / 256, 256, 0, stream>>>(offsets, bbase, cursor);
  reorder_kernel<<<(N_EDGES + 255) / 256, 256, 0, stream>>>(ei, cursor, srcs);
  node_gemm_kernel<<<(N_NODES + 63) / 64, 256, 0, stream>>>(xb, wt, w1t2, b, b1, uxt, vout);
  edge_fused_kernel<<<(N_NODES * 64 + 255) / 256, 256, 0, stream>>>(
      uxt, vout, offsets, srcs, W2, b2, out);
}

// Round 12
// 169.703 us; speedup vs baseline: 4.1868x; 1.0606x over previous
//
#include <hip/hip_runtime.h>

#define N_NODES 50000
#define N_EDGES 800000
#define F 128
#define ROWB 384   // uxt row: [0,128)=u fp8, [128,384)=xt bf16

typedef unsigned short u16;
typedef __bf16 bf16x8 __attribute__((ext_vector_type(8)));
typedef float f32x4 __attribute__((ext_vector_type(4)));
typedef float f32x2 __attribute__((ext_vector_type(2)));

__device__ inline u16 f2bf(float f) {
  union { float f; unsigned u; } v; v.f = f;
  unsigned r = v.u + 0x7fffu + ((v.u >> 16) & 1u);
  return (u16)(r >> 16);
}

__device__ inline int clampi(int v) {
  v = v < 0 ? 0 : v;
  return v >= N_NODES ? N_NODES - 1 : v;
}

// fp8 e4m3 cvt via HW instruction (builtin if present, else inline asm)
__device__ inline f32x2 fp8x2_to_f32(unsigned w) {
#if __has_builtin(__builtin_amdgcn_cvt_pk_f32_fp8)
  return __builtin_amdgcn_cvt_pk_f32_fp8((int)w, false);
#else
  f32x2 r;
  asm("v_cvt_pk_f32_fp8 %0, %1" : "=v"(r) : "v"(w));
  return r;
#endif
}
__device__ inline unsigned f32_to_fp8(float a) {
#if __has_builtin(__builtin_amdgcn_cvt_pk_fp8_f32)
  return (unsigned)__builtin_amdgcn_cvt_pk_fp8_f32(a, a, 0, false) & 0xffu;
#else
  unsigned r;
  asm("v_cvt_pk_fp8_f32 %0, %1, %2" : "=v"(r) : "v"(a), "v"(a));
  return r & 0xffu;
#endif
}

// load 8 contiguous fp32 -> bf16x8 fragment
__device__ inline bf16x8 pack8(const float* __restrict__ p) {
  float4 a = *(const float4*)p;
  float4 b = *(const float4*)(p + 4);
  bf16x8 r;
  r[0] = (__bf16)a.x; r[1] = (__bf16)a.y; r[2] = (__bf16)a.z; r[3] = (__bf16)a.w;
  r[4] = (__bf16)b.x; r[5] = (__bf16)b.y; r[6] = (__bf16)b.z; r[7] = (__bf16)b.w;
  return r;
}

// ---------- zero degree counters ----------
__global__ void zero_deg_kernel(int* __restrict__ deg) {
  int i = blockIdx.x * blockDim.x + threadIdx.x;
  if (i < N_NODES) deg[i] = 0;
}

// ---------- fused setup: transpose weights | dst histogram ----------
#define PREP_BLOCKS 192
#define HIST_BLOCKS 832
__global__ __launch_bounds__(256) void setup_kernel(
    const float* __restrict__ W, const float* __restrict__ W1,
    u16* __restrict__ wt, u16* __restrict__ w1t2,
    const int* __restrict__ ei, int* __restrict__ deg)
{
  int bid = blockIdx.x;
  if (bid < PREP_BLOCKS) {
    int t = bid * 256 + threadIdx.x;  // 0 .. 49151
    if (t < 128 * 128) {
      int k = t >> 7, n = t & 127;
      wt[n * 128 + k] = f2bf(W[k * 128 + n]);
    } else {
      int t2 = t - 128 * 128;           // 0 .. 32767
      int n2 = t2 >> 7, k = t2 & 127;   // n2: 0..255
      float v = (n2 < 128) ? W1[k * 128 + n2] : W1[(128 + k) * 128 + (n2 - 128)];
      w1t2[n2 * 128 + k] = f2bf(v);
    }
  } else {
    int stride = HIST_BLOCKS * 256;
    for (int e = (bid - PREP_BLOCKS) * 256 + threadIdx.x; e < N_EDGES; e += stride)
      atomicAdd(&deg[clampi(ei[N_EDGES + e])], 1);
  }
}

// ---------- hierarchical scan: 49-block partial scan ----------
#define SCAN_BLOCKS 49
__global__ __launch_bounds__(1024) void scan1_kernel(const int* __restrict__ deg,
                                                     int* __restrict__ offsets,
                                                     int* __restrict__ bsum) {
  __shared__ int wsum[16];
  int t = threadIdx.x, lane = t & 63, wid = t >> 6;
  int i = blockIdx.x * 1024 + t;
  int v = (i < N_NODES) ? deg[i] : 0;
  int s = v;
#pragma unroll
  for (int d = 1; d < 64; d <<= 1) {
    int u = __shfl_up(s, d);
    if (lane >= d) s += u;
  }
  if (lane == 63) wsum[wid] = s;
  __syncthreads();
  if (wid == 0 && lane < 16) {
    int ws = wsum[lane];
#pragma unroll
    for (int d = 1; d < 16; d <<= 1) {
      int u = __shfl_up(ws, d);
      if (lane >= d) ws += u;
    }
    wsum[lane] = ws;
  }
  __syncthreads();
  int wprev = (wid == 0) ? 0 : wsum[wid - 1];
  if (i < N_NODES) offsets[i] = wprev + s - v;  // block-local exclusive
  if (t == 0) bsum[blockIdx.x] = wsum[15];
}

// ---------- scan of block sums (redundant per block) + add base + cursor ----------
__global__ __launch_bounds__(256) void scan23_kernel(int* __restrict__ offsets,
                                                     const int* __restrict__ bsum,
                                                     int* __restrict__ cursor) {
  __shared__ int base[SCAN_BLOCKS + 1];
  if (threadIdx.x < 64) {
    int t = threadIdx.x;
    int v = (t < SCAN_BLOCKS) ? bsum[t] : 0;
    int s = v;
#pragma unroll
    for (int d = 1; d < 64; d <<= 1) {
      int u = __shfl_up(s, d);
      if (t >= d) s += u;
    }
    if (t < SCAN_BLOCKS) base[t] = s - v;
    if (t == SCAN_BLOCKS - 1) base[SCAN_BLOCKS] = s;
  }
  __syncthreads();
  int i = blockIdx.x * blockDim.x + threadIdx.x;
  if (i < N_NODES) {
    int off = offsets[i] + base[i >> 10];
    offsets[i] = off;
    cursor[i] = off;
  }
  if (i == 0) offsets[N_NODES] = base[SCAN_BLOCKS];
}

// ---------- reorder: srcs[p] = src of p-th dst-sorted edge ----------
__global__ void reorder_kernel(const int* __restrict__ ei, int* __restrict__ cursor,
                               int* __restrict__ srcs) {
  int e = blockIdx.x * blockDim.x + threadIdx.x;
  if (e < N_EDGES) {
    int s = clampi(ei[e]);
    int d = clampi(ei[N_EDGES + e]);
    int p = atomicAdd(&cursor[d], 1);
    srcs[p] = s;
  }
}

// ---------- node GEMMs: xt(bf16), u(fp8), v(bf16); x read fp32 once ----------
__global__ __launch_bounds__(256) void node_gemm_kernel(
    const float* __restrict__ x, const u16* __restrict__ wt,
    const u16* __restrict__ w1t2, const float* __restrict__ bias,
    const float* __restrict__ b1,
    unsigned char* __restrict__ uxt, u16* __restrict__ vout)
{
  __shared__ u16 wl[128 * 128];  // 32KB, slot XOR-swizzled by (row&7)
  int w = threadIdx.x >> 6, l = threadIdx.x & 63;
  int r2 = l & 15, q = l >> 4;
  int sw = r2 & 7;
  int rowbase = blockIdx.x * 64 + w * 16;
  int ra = rowbase + r2;  if (ra >= N_NODES) ra = N_NODES - 1;
  // A-fragments: fp32 load + cvt, once, reused by all three GEMMs
  bf16x8 A[4];
#pragma unroll
  for (int k = 0; k < 4; k++)
    A[k] = pack8(x + ra * F + q * 8 + 32 * k);

  // ---- phase 1: stage wt; xt = x@W + b -> uxt[.][128:384) bf16 ----
  for (int c = threadIdx.x; c < 128 * 16; c += 256) {
    int row = c >> 4, slot = c & 15;
    *(bf16x8*)&wl[row * 128 + ((slot ^ (row & 7)) << 3)] =
        *(const bf16x8*)(wt + row * 128 + slot * 8);
  }
  __syncthreads();
  {
    float bv[8];
#pragma unroll
    for (int nf = 0; nf < 8; nf++) bv[nf] = bias[r2 + 16 * nf];
    f32x4 acc[8] = {};
#pragma unroll
    for (int k = 0; k < 4; k++) {
#pragma unroll
      for (int nf = 0; nf < 8; nf++) {
        bf16x8 b = *(const bf16x8*)&wl[(16 * nf + r2) * 128 + (((q + 4 * k) ^ sw) << 3)];
        acc[nf] = __builtin_amdgcn_mfma_f32_16x16x32_bf16(A[k], b, acc[nf], 0, 0, 0);
      }
    }
#pragma unroll
    for (int nf = 0; nf < 8; nf++) {
#pragma unroll
      for (int r = 0; r < 4; r++) {
        int row = rowbase + 4 * q + r;
        int c = r2 + 16 * nf;
        if (row < N_NODES)
          *(u16*)(uxt + (size_t)row * ROWB + 128 + 2 * c) = f2bf(acc[nf][r] + bv[nf]);
      }
    }
  }
  __syncthreads();
  // ---- phase 2: stage W1s; u = x@W1s -> uxt[.][0:128) fp8 ----
  for (int c = threadIdx.x; c < 128 * 16; c += 256) {
    int row = c >> 4, slot = c & 15;
    *(bf16x8*)&wl[row * 128 + ((slot ^ (row & 7)) << 3)] =
        *(const bf16x8*)(w1t2 + row * 128 + slot * 8);
  }
  __syncthreads();
  {
    f32x4 acc[8] = {};
#pragma unroll
    for (int k = 0; k < 4; k++) {
#pragma unroll
      for (int nf = 0; nf < 8; nf++) {
        bf16x8 b = *(const bf16x8*)&wl[(16 * nf + r2) * 128 + (((q + 4 * k) ^ sw) << 3)];
        acc[nf] = __builtin_amdgcn_mfma_f32_16x16x32_bf16(A[k], b, acc[nf], 0, 0, 0);
      }
    }
#pragma unroll
    for (int nf = 0; nf < 8; nf++) {
#pragma unroll
      for (int r = 0; r < 4; r++) {
        int row = rowbase + 4 * q + r;
        int c = r2 + 16 * nf;
        if (row < N_NODES)
          uxt[(size_t)row * ROWB + c] = (unsigned char)f32_to_fp8(acc[nf][r]);
      }
    }
  }
  __syncthreads();
  // ---- phase 3: stage W1d; v = x@W1d + b1 -> vout bf16 ----
  for (int c = threadIdx.x; c < 128 * 16; c += 256) {
    int row = c >> 4, slot = c & 15;
    *(bf16x8*)&wl[row * 128 + ((slot ^ (row & 7)) << 3)] =
        *(const bf16x8*)(w1t2 + 128 * 128 + row * 128 + slot * 8);
  }
  __syncthreads();
  {
    float b1v[8];
#pragma unroll
    for (int nf = 0; nf < 8; nf++) b1v[nf] = b1[r2 + 16 * nf];
    f32x4 acc[8] = {};
#pragma unroll
    for (int k = 0; k < 4; k++) {
#pragma unroll
      for (int nf = 0; nf < 8; nf++) {
        bf16x8 b = *(const bf16x8*)&wl[(16 * nf + r2) * 128 + (((q + 4 * k) ^ sw) << 3)];
        acc[nf] = __builtin_amdgcn_mfma_f32_16x16x32_bf16(A[k], b, acc[nf], 0, 0, 0);
      }
    }
#pragma unroll
    for (int nf = 0; nf < 8; nf++) {
#pragma unroll
      for (int r = 0; r < 4; r++) {
        int row = rowbase + 4 * q + r;
        int c = r2 + 16 * nf;
        if (row < N_NODES) vout[row * F + c] = f2bf(acc[nf][r] + b1v[nf]);
      }
    }
  }
}

// ---------- fused gate + aggregate: one wave per dst node ----------
__global__ __launch_bounds__(256) void edge_fused_kernel(
    const unsigned char* __restrict__ uxt, const u16* __restrict__ v,
    const int* __restrict__ offsets, const int* __restrict__ srcs,
    const float* __restrict__ w2f, const float* __restrict__ b2,
    float* __restrict__ out)
{
  int n = (blockIdx.x * blockDim.x + threadIdx.x) >> 6;
  if (n >= N_NODES) return;
  int lane = threadIdx.x & 63;
  int g = lane >> 4, j = lane & 15;
  float w2v[8], vn[8];
  float4 wa = *(const float4*)(w2f + 8 * j);
  float4 wb = *(const float4*)(w2f + 8 * j + 4);
  w2v[0] = wa.x; w2v[1] = wa.y; w2v[2] = wa.z; w2v[3] = wa.w;
  w2v[4] = wb.x; w2v[5] = wb.y; w2v[6] = wb.z; w2v[7] = wb.w;
  bf16x8 vv = *(const bf16x8*)(v + n * F + 8 * j);
#pragma unroll
  for (int i = 0; i < 8; i++) vn[i] = (float)vv[i];
  float bias2 = b2[0];
  float acc[8] = {};
  int p = offsets[n], end = offsets[n + 1];
  for (int base = p; base < end; base += 4) {
    int slot = base + g;
    bool valid = slot < end;
    int sp = srcs[valid ? slot : end - 1];
    const unsigned char* row = uxt + (size_t)sp * ROWB;
    uint2 up = *(const uint2*)(row + 8 * j);            // 8 fp8 u values
    bf16x8 xx = *(const bf16x8*)(row + 128 + 16 * j);   // 8 bf16 xt values
    f32x2 u01 = fp8x2_to_f32(up.x & 0xffffu);
    f32x2 u23 = fp8x2_to_f32(up.x >> 16);
    f32x2 u45 = fp8x2_to_f32(up.y & 0xffffu);
    f32x2 u67 = fp8x2_to_f32(up.y >> 16);
    float uu[8] = {u01[0], u01[1], u23[0], u23[1], u45[0], u45[1], u67[0], u67[1]};
    float t = 0.f;
#pragma unroll
    for (int i = 0; i < 8; i++) {
      float h = uu[i] + vn[i];
      h = h > 0.f ? h : 0.f;
      t += h * w2v[i];
    }
    t += __shfl_xor(t, 1);
    t += __shfl_xor(t, 2);
    t += __shfl_xor(t, 4);
    t += __shfl_xor(t, 8);
    float gate = valid ? 1.0f / (1.0f + __expf(-(t + bias2))) : 0.f;
#pragma unroll
    for (int i = 0; i < 8; i++) acc[i] += gate * (float)xx[i];
  }
#pragma unroll
  for (int i = 0; i < 8; i++) acc[i] += __shfl_xor(acc[i], 16);
#pragma unroll
  for (int i = 0; i < 8; i++) acc[i] += __shfl_xor(acc[i], 32);
  if (g == 0) {
    float4 o0, o1;
    o0.x = acc[0]; o0.y = acc[1]; o0.z = acc[2]; o0.w = acc[3];
    o1.x = acc[4]; o1.y = acc[5]; o1.z = acc[6]; o1.w = acc[7];
    *(float4*)(out + n * F + 8 * j) = o0;
    *(float4*)(out + n * F + 8 * j + 4) = o1;
  }
}

extern "C" void kernel_launch(void* const* d_in, const int* in_sizes, int n_in,
                              void* d_out, int out_size, void* d_ws, size_t ws_size,
                              hipStream_t stream) {
  const float* x  = (const float*)d_in[0];
  const int* ei   = (const int*)d_in[1];   // int64 in reference -> int32 in harness
  const float* W  = (const float*)d_in[2];
  const float* b  = (const float*)d_in[3];
  const float* W1 = (const float*)d_in[4];
  const float* b1 = (const float*)d_in[5];
  const float* W2 = (const float*)d_in[6];
  const float* b2 = (const float*)d_in[7];
  float* out = (float*)d_out;

  char* ws = (char*)d_ws;
  unsigned char* uxt = (unsigned char*)ws;    // 19,200,000 B  [n]: u fp8 | xt bf16
  u16* vout    = (u16*)(ws + 19200000);       // 12,800,000 B
  u16* wt      = (u16*)(ws + 32000000);       //     32,768 B
  u16* w1t2    = (u16*)(ws + 32032768);       //     65,536 B
  int* offsets = (int*)(ws + 32098304);       //    200,004 B
  int* deg     = (int*)(ws + 32298308);       //    200,000 B
  int* cursor  = (int*)(ws + 32498308);       //    200,000 B
  int* srcs    = (int*)(ws + 32698308);       //  3,200,000 B
  int* bsum    = (int*)(ws + 35898308);       //        196 B   total ~35.9 MB
  (void)ws_size;

  zero_deg_kernel<<<(N_NODES + 255) / 256, 256, 0, stream>>>(deg);
  setup_kernel<<<PREP_BLOCKS + HIST_BLOCKS, 256, 0, stream>>>(W, W1, wt, w1t2, ei, deg);
  scan1_kernel<<<SCAN_BLOCKS, 1024, 0, stream>>>(deg, offsets, bsum);
  scan23_kernel<<<(N_NODES + 255) / 256, 256, 0, stream>>>(offsets, bsum, cursor);
  reorder_kernel<<<(N_EDGES + 255) / 256, 256, 0, stream>>>(ei, cursor, srcs);
  node_gemm_kernel<<<(N_NODES + 63) / 64, 256, 0, stream>>>(x, wt, w1t2, b, b1, uxt, vout);
  edge_fused_kernel<<<(N_NODES * 64 + 255) / 256, 256, 0, stream>>>(
      uxt, vout, offsets, srcs, W2, b2, out);
}

// Round 13
// 131.278 us; speedup vs baseline: 5.4122x; 1.2927x over previous
//
#include <hip/hip_runtime.h>

#define N_NODES 50000
#define N_EDGES 800000
#define F 128
#define ROWB 384   // uxt row: [0,128)=u fp8, [128,384)=xt bf16

typedef unsigned short u16;
typedef __bf16 bf16x8 __attribute__((ext_vector_type(8)));
typedef float f32x4 __attribute__((ext_vector_type(4)));
typedef float f32x2 __attribute__((ext_vector_type(2)));

__device__ inline u16 f2bf(float f) {
  union { float f; unsigned u; } v; v.f = f;
  unsigned r = v.u + 0x7fffu + ((v.u >> 16) & 1u);
  return (u16)(r >> 16);
}

__device__ inline int clampi(int v) {
  v = v < 0 ? 0 : v;
  return v >= N_NODES ? N_NODES - 1 : v;
}

// fp8 e4m3 cvt via HW instruction (builtin if present, else inline asm)
__device__ inline f32x2 fp8x2_to_f32(unsigned w) {
#if __has_builtin(__builtin_amdgcn_cvt_pk_f32_fp8)
  return __builtin_amdgcn_cvt_pk_f32_fp8((int)w, false);
#else
  f32x2 r;
  asm("v_cvt_pk_f32_fp8 %0, %1" : "=v"(r) : "v"(w));
  return r;
#endif
}
__device__ inline unsigned f32_to_fp8(float a) {
#if __has_builtin(__builtin_amdgcn_cvt_pk_fp8_f32)
  return (unsigned)__builtin_amdgcn_cvt_pk_fp8_f32(a, a, 0, false) & 0xffu;
#else
  unsigned r;
  asm("v_cvt_pk_fp8_f32 %0, %1, %2" : "=v"(r) : "v"(a), "v"(a));
  return r & 0xffu;
#endif
}

// load 8 contiguous fp32 -> bf16x8 fragment
__device__ inline bf16x8 pack8(const float* __restrict__ p) {
  float4 a = *(const float4*)p;
  float4 b = *(const float4*)(p + 4);
  bf16x8 r;
  r[0] = (__bf16)a.x; r[1] = (__bf16)a.y; r[2] = (__bf16)a.z; r[3] = (__bf16)a.w;
  r[4] = (__bf16)b.x; r[5] = (__bf16)b.y; r[6] = (__bf16)b.z; r[7] = (__bf16)b.w;
  return r;
}

// ---------- zero degree counters ----------
__global__ void zero_deg_kernel(int* __restrict__ deg) {
  int i = blockIdx.x * blockDim.x + threadIdx.x;
  if (i < N_NODES) deg[i] = 0;
}

// ---------- fused setup: transpose weights | dst histogram + per-edge rank ----------
#define PREP_BLOCKS 192
#define HIST_BLOCKS 832
__global__ __launch_bounds__(256) void setup_kernel(
    const float* __restrict__ W, const float* __restrict__ W1,
    u16* __restrict__ wt, u16* __restrict__ w1t2,
    const int* __restrict__ ei, int* __restrict__ deg, int* __restrict__ loc)
{
  int bid = blockIdx.x;
  if (bid < PREP_BLOCKS) {
    int t = bid * 256 + threadIdx.x;  // 0 .. 49151
    if (t < 128 * 128) {
      int k = t >> 7, n = t & 127;
      wt[n * 128 + k] = f2bf(W[k * 128 + n]);
    } else {
      int t2 = t - 128 * 128;           // 0 .. 32767
      int n2 = t2 >> 7, k = t2 & 127;   // n2: 0..255
      float v = (n2 < 128) ? W1[k * 128 + n2] : W1[(128 + k) * 128 + (n2 - 128)];
      w1t2[n2 * 128 + k] = f2bf(v);
    }
  } else {
    int stride = HIST_BLOCKS * 256;
    for (int e = (bid - PREP_BLOCKS) * 256 + threadIdx.x; e < N_EDGES; e += stride)
      loc[e] = atomicAdd(&deg[clampi(ei[N_EDGES + e])], 1);
  }
}

// ---------- hierarchical scan: 49-block partial scan ----------
#define SCAN_BLOCKS 49
__global__ __launch_bounds__(1024) void scan1_kernel(const int* __restrict__ deg,
                                                     int* __restrict__ offsets,
                                                     int* __restrict__ bsum) {
  __shared__ int wsum[16];
  int t = threadIdx.x, lane = t & 63, wid = t >> 6;
  int i = blockIdx.x * 1024 + t;
  int v = (i < N_NODES) ? deg[i] : 0;
  int s = v;
#pragma unroll
  for (int d = 1; d < 64; d <<= 1) {
    int u = __shfl_up(s, d);
    if (lane >= d) s += u;
  }
  if (lane == 63) wsum[wid] = s;
  __syncthreads();
  if (wid == 0 && lane < 16) {
    int ws = wsum[lane];
#pragma unroll
    for (int d = 1; d < 16; d <<= 1) {
      int u = __shfl_up(ws, d);
      if (lane >= d) ws += u;
    }
    wsum[lane] = ws;
  }
  __syncthreads();
  int wprev = (wid == 0) ? 0 : wsum[wid - 1];
  if (i < N_NODES) offsets[i] = wprev + s - v;  // block-local exclusive
  if (t == 0) bsum[blockIdx.x] = wsum[15];
}

// ---------- scan of block sums (redundant per block) + add base ----------
__global__ __launch_bounds__(256) void scan23_kernel(int* __restrict__ offsets,
                                                     const int* __restrict__ bsum) {
  __shared__ int base[SCAN_BLOCKS + 1];
  if (threadIdx.x < 64) {
    int t = threadIdx.x;
    int v = (t < SCAN_BLOCKS) ? bsum[t] : 0;
    int s = v;
#pragma unroll
    for (int d = 1; d < 64; d <<= 1) {
      int u = __shfl_up(s, d);
      if (t >= d) s += u;
    }
    if (t < SCAN_BLOCKS) base[t] = s - v;
    if (t == SCAN_BLOCKS - 1) base[SCAN_BLOCKS] = s;
  }
  __syncthreads();
  int i = blockIdx.x * blockDim.x + threadIdx.x;
  if (i < N_NODES) offsets[i] += base[i >> 10];
  if (i == 0) offsets[N_NODES] = base[SCAN_BLOCKS];
}

// ---------- reorder: atomic-free scatter, srcs16[offsets[d]+loc[e]] = src ----------
__global__ void reorder_kernel(const int* __restrict__ ei, const int* __restrict__ offsets,
                               const int* __restrict__ loc, u16* __restrict__ srcs16) {
  int e = blockIdx.x * blockDim.x + threadIdx.x;
  if (e < N_EDGES) {
    int s = clampi(ei[e]);
    int d = clampi(ei[N_EDGES + e]);
    srcs16[offsets[d] + loc[e]] = (u16)s;
  }
}

// ---------- node GEMMs: xt(bf16), u(fp8), v(bf16); x read fp32 once ----------
__global__ __launch_bounds__(256) void node_gemm_kernel(
    const float* __restrict__ x, const u16* __restrict__ wt,
    const u16* __restrict__ w1t2, const float* __restrict__ bias,
    const float* __restrict__ b1,
    unsigned char* __restrict__ uxt, u16* __restrict__ vout)
{
  __shared__ u16 wl[128 * 128];  // 32KB, slot XOR-swizzled by (row&7)
  int w = threadIdx.x >> 6, l = threadIdx.x & 63;
  int r2 = l & 15, q = l >> 4;
  int sw = r2 & 7;
  int rowbase = blockIdx.x * 64 + w * 16;
  int ra = rowbase + r2;  if (ra >= N_NODES) ra = N_NODES - 1;
  bf16x8 A[4];
#pragma unroll
  for (int k = 0; k < 4; k++)
    A[k] = pack8(x + ra * F + q * 8 + 32 * k);

  // ---- phase 1: stage wt; xt = x@W + b -> uxt[.][128:384) bf16 ----
  for (int c = threadIdx.x; c < 128 * 16; c += 256) {
    int row = c >> 4, slot = c & 15;
    *(bf16x8*)&wl[row * 128 + ((slot ^ (row & 7)) << 3)] =
        *(const bf16x8*)(wt + row * 128 + slot * 8);
  }
  __syncthreads();
  {
    float bv[8];
#pragma unroll
    for (int nf = 0; nf < 8; nf++) bv[nf] = bias[r2 + 16 * nf];
    f32x4 acc[8] = {};
#pragma unroll
    for (int k = 0; k < 4; k++) {
#pragma unroll
      for (int nf = 0; nf < 8; nf++) {
        bf16x8 b = *(const bf16x8*)&wl[(16 * nf + r2) * 128 + (((q + 4 * k) ^ sw) << 3)];
        acc[nf] = __builtin_amdgcn_mfma_f32_16x16x32_bf16(A[k], b, acc[nf], 0, 0, 0);
      }
    }
#pragma unroll
    for (int nf = 0; nf < 8; nf++) {
#pragma unroll
      for (int r = 0; r < 4; r++) {
        int row = rowbase + 4 * q + r;
        int c = r2 + 16 * nf;
        if (row < N_NODES)
          *(u16*)(uxt + (size_t)row * ROWB + 128 + 2 * c) = f2bf(acc[nf][r] + bv[nf]);
      }
    }
  }
  __syncthreads();
  // ---- phase 2: stage W1s; u = x@W1s -> uxt[.][0:128) fp8 ----
  for (int c = threadIdx.x; c < 128 * 16; c += 256) {
    int row = c >> 4, slot = c & 15;
    *(bf16x8*)&wl[row * 128 + ((slot ^ (row & 7)) << 3)] =
        *(const bf16x8*)(w1t2 + row * 128 + slot * 8);
  }
  __syncthreads();
  {
    f32x4 acc[8] = {};
#pragma unroll
    for (int k = 0; k < 4; k++) {
#pragma unroll
      for (int nf = 0; nf < 8; nf++) {
        bf16x8 b = *(const bf16x8*)&wl[(16 * nf + r2) * 128 + (((q + 4 * k) ^ sw) << 3)];
        acc[nf] = __builtin_amdgcn_mfma_f32_16x16x32_bf16(A[k], b, acc[nf], 0, 0, 0);
      }
    }
#pragma unroll
    for (int nf = 0; nf < 8; nf++) {
#pragma unroll
      for (int r = 0; r < 4; r++) {
        int row = rowbase + 4 * q + r;
        int c = r2 + 16 * nf;
        if (row < N_NODES)
          uxt[(size_t)row * ROWB + c] = (unsigned char)f32_to_fp8(acc[nf][r]);
      }
    }
  }
  __syncthreads();
  // ---- phase 3: stage W1d; v = x@W1d + b1 -> vout bf16 ----
  for (int c = threadIdx.x; c < 128 * 16; c += 256) {
    int row = c >> 4, slot = c & 15;
    *(bf16x8*)&wl[row * 128 + ((slot ^ (row & 7)) << 3)] =
        *(const bf16x8*)(w1t2 + 128 * 128 + row * 128 + slot * 8);
  }
  __syncthreads();
  {
    float b1v[8];
#pragma unroll
    for (int nf = 0; nf < 8; nf++) b1v[nf] = b1[r2 + 16 * nf];
    f32x4 acc[8] = {};
#pragma unroll
    for (int k = 0; k < 4; k++) {
#pragma unroll
      for (int nf = 0; nf < 8; nf++) {
        bf16x8 b = *(const bf16x8*)&wl[(16 * nf + r2) * 128 + (((q + 4 * k) ^ sw) << 3)];
        acc[nf] = __builtin_amdgcn_mfma_f32_16x16x32_bf16(A[k], b, acc[nf], 0, 0, 0);
      }
    }
#pragma unroll
    for (int nf = 0; nf < 8; nf++) {
#pragma unroll
      for (int r = 0; r < 4; r++) {
        int row = rowbase + 4 * q + r;
        int c = r2 + 16 * nf;
        if (row < N_NODES) vout[row * F + c] = f2bf(acc[nf][r] + b1v[nf]);
      }
    }
  }
}

// ---------- fused gate + aggregate: one wave per dst node ----------
__global__ __launch_bounds__(256) void edge_fused_kernel(
    const unsigned char* __restrict__ uxt, const u16* __restrict__ v,
    const int* __restrict__ offsets, const u16* __restrict__ srcs16,
    const float* __restrict__ w2f, const float* __restrict__ b2,
    float* __restrict__ out)
{
  int n = (blockIdx.x * blockDim.x + threadIdx.x) >> 6;
  if (n >= N_NODES) return;
  int lane = threadIdx.x & 63;
  int g = lane >> 4, j = lane & 15;
  float w2v[8], vn[8];
  float4 wa = *(const float4*)(w2f + 8 * j);
  float4 wb = *(const float4*)(w2f + 8 * j + 4);
  w2v[0] = wa.x; w2v[1] = wa.y; w2v[2] = wa.z; w2v[3] = wa.w;
  w2v[4] = wb.x; w2v[5] = wb.y; w2v[6] = wb.z; w2v[7] = wb.w;
  bf16x8 vv = *(const bf16x8*)(v + n * F + 8 * j);
#pragma unroll
  for (int i = 0; i < 8; i++) vn[i] = (float)vv[i];
  float bias2 = b2[0];
  float acc[8] = {};
  int p = offsets[n], end = offsets[n + 1];
  for (int base = p; base < end; base += 4) {
    int slot = base + g;
    bool valid = slot < end;
    int sp = srcs16[valid ? slot : end - 1];
    const unsigned char* row = uxt + (size_t)sp * ROWB;
    uint2 up = *(const uint2*)(row + 8 * j);            // 8 fp8 u values
    bf16x8 xx = *(const bf16x8*)(row + 128 + 16 * j);   // 8 bf16 xt values
    f32x2 u01 = fp8x2_to_f32(up.x & 0xffffu);
    f32x2 u23 = fp8x2_to_f32(up.x >> 16);
    f32x2 u45 = fp8x2_to_f32(up.y & 0xffffu);
    f32x2 u67 = fp8x2_to_f32(up.y >> 16);
    float uu[8] = {u01[0], u01[1], u23[0], u23[1], u45[0], u45[1], u67[0], u67[1]};
    float t = 0.f;
#pragma unroll
    for (int i = 0; i < 8; i++) {
      float h = uu[i] + vn[i];
      h = h > 0.f ? h : 0.f;
      t += h * w2v[i];
    }
    t += __shfl_xor(t, 1);
    t += __shfl_xor(t, 2);
    t += __shfl_xor(t, 4);
    t += __shfl_xor(t, 8);
    float gate = valid ? 1.0f / (1.0f + __expf(-(t + bias2))) : 0.f;
#pragma unroll
    for (int i = 0; i < 8; i++) acc[i] += gate * (float)xx[i];
  }
#pragma unroll
  for (int i = 0; i < 8; i++) acc[i] += __shfl_xor(acc[i], 16);
#pragma unroll
  for (int i = 0; i < 8; i++) acc[i] += __shfl_xor(acc[i], 32);
  if (g == 0) {
    float4 o0, o1;
    o0.x = acc[0]; o0.y = acc[1]; o0.z = acc[2]; o0.w = acc[3];
    o1.x = acc[4]; o1.y = acc[5]; o1.z = acc[6]; o1.w = acc[7];
    *(float4*)(out + n * F + 8 * j) = o0;
    *(float4*)(out + n * F + 8 * j + 4) = o1;
  }
}

extern "C" void kernel_launch(void* const* d_in, const int* in_sizes, int n_in,
                              void* d_out, int out_size, void* d_ws, size_t ws_size,
                              hipStream_t stream) {
  const float* x  = (const float*)d_in[0];
  const int* ei   = (const int*)d_in[1];   // int64 in reference -> int32 in harness
  const float* W  = (const float*)d_in[2];
  const float* b  = (const float*)d_in[3];
  const float* W1 = (const float*)d_in[4];
  const float* b1 = (const float*)d_in[5];
  const float* W2 = (const float*)d_in[6];
  const float* b2 = (const float*)d_in[7];
  float* out = (float*)d_out;

  char* ws = (char*)d_ws;
  unsigned char* uxt = (unsigned char*)ws;    // 19,200,000 B  [n]: u fp8 | xt bf16
  u16* vout    = (u16*)(ws + 19200000);       // 12,800,000 B
  u16* wt      = (u16*)(ws + 32000000);       //     32,768 B
  u16* w1t2    = (u16*)(ws + 32032768);       //     65,536 B
  int* offsets = (int*)(ws + 32098304);       //    200,004 B
  int* deg     = (int*)(ws + 32298308);       //    200,000 B
  int* loc     = (int*)(ws + 32498308);       //  3,200,000 B
  u16* srcs16  = (u16*)(ws + 35698308);       //  1,600,000 B
  int* bsum    = (int*)(ws + 37298308);       //        196 B   total ~37.3 MB
  (void)ws_size;

  zero_deg_kernel<<<(N_NODES + 255) / 256, 256, 0, stream>>>(deg);
  setup_kernel<<<PREP_BLOCKS + HIST_BLOCKS, 256, 0, stream>>>(W, W1, wt, w1t2, ei, deg, loc);
  scan1_kernel<<<SCAN_BLOCKS, 1024, 0, stream>>>(deg, offsets, bsum);
  scan23_kernel<<<(N_NODES + 255) / 256, 256, 0, stream>>>(offsets, bsum);
  reorder_kernel<<<(N_EDGES + 255) / 256, 256, 0, stream>>>(ei, offsets, loc, srcs16);
  node_gemm_kernel<<<(N_NODES + 63) / 64, 256, 0, stream>>>(x, wt, w1t2, b, b1, uxt, vout);
  edge_fused_kernel<<<(N_NODES * 64 + 255) / 256, 256, 0, stream>>>(
      uxt, vout, offsets, srcs16, W2, b2, out);
}

// Round 14
// 127.122 us; speedup vs baseline: 5.5892x; 1.0327x over previous
//
#include <hip/hip_runtime.h>

#define N_NODES 50000
#define N_EDGES 800000
#define F 128
#define ROWB 384   // uxt row: [0,128)=u fp8, [128,384)=xt bf16

typedef unsigned short u16;
typedef __bf16 bf16x8 __attribute__((ext_vector_type(8)));
typedef float f32x4 __attribute__((ext_vector_type(4)));
typedef float f32x2 __attribute__((ext_vector_type(2)));

__device__ inline u16 f2bf(float f) {
  union { float f; unsigned u; } v; v.f = f;
  unsigned r = v.u + 0x7fffu + ((v.u >> 16) & 1u);
  return (u16)(r >> 16);
}

__device__ inline int clampi(int v) {
  v = v < 0 ? 0 : v;
  return v >= N_NODES ? N_NODES - 1 : v;
}

// fp8 e4m3 cvt via HW instruction (builtin if present, else inline asm)
__device__ inline f32x2 fp8x2_to_f32(unsigned w) {
#if __has_builtin(__builtin_amdgcn_cvt_pk_f32_fp8)
  return __builtin_amdgcn_cvt_pk_f32_fp8((int)w, false);
#else
  f32x2 r;
  asm("v_cvt_pk_f32_fp8 %0, %1" : "=v"(r) : "v"(w));
  return r;
#endif
}
__device__ inline unsigned f32_to_fp8(float a) {
#if __has_builtin(__builtin_amdgcn_cvt_pk_fp8_f32)
  return (unsigned)__builtin_amdgcn_cvt_pk_fp8_f32(a, a, 0, false) & 0xffu;
#else
  unsigned r;
  asm("v_cvt_pk_fp8_f32 %0, %1, %2" : "=v"(r) : "v"(a), "v"(a));
  return r & 0xffu;
#endif
}

// load 8 contiguous fp32 -> bf16x8 fragment
__device__ inline bf16x8 pack8(const float* __restrict__ p) {
  float4 a = *(const float4*)p;
  float4 b = *(const float4*)(p + 4);
  bf16x8 r;
  r[0] = (__bf16)a.x; r[1] = (__bf16)a.y; r[2] = (__bf16)a.z; r[3] = (__bf16)a.w;
  r[4] = (__bf16)b.x; r[5] = (__bf16)b.y; r[6] = (__bf16)b.z; r[7] = (__bf16)b.w;
  return r;
}

// ---------- pre: zero deg | transpose weights (disjoint block ranges) ----------
#define ZERO_BLOCKS 196
#define PREP_BLOCKS 192
__global__ __launch_bounds__(256) void pre_kernel(
    int* __restrict__ deg,
    const float* __restrict__ W, const float* __restrict__ W1,
    u16* __restrict__ wt, u16* __restrict__ w1t2)
{
  int bid = blockIdx.x;
  if (bid < ZERO_BLOCKS) {
    int i = bid * 256 + threadIdx.x;
    if (i < N_NODES) deg[i] = 0;
  } else {
    int t = (bid - ZERO_BLOCKS) * 256 + threadIdx.x;  // 0 .. 49151
    if (t < 128 * 128) {
      int k = t >> 7, n = t & 127;
      wt[n * 128 + k] = f2bf(W[k * 128 + n]);
    } else {
      int t2 = t - 128 * 128;           // 0 .. 32767
      int n2 = t2 >> 7, k = t2 & 127;   // n2: 0..255
      float v = (n2 < 128) ? W1[k * 128 + n2] : W1[(128 + k) * 128 + (n2 - 128)];
      w1t2[n2 * 128 + k] = f2bf(v);
    }
  }
}

// ---------- heavy: hist+loc (blocks [0,HIST)) | node GEMMs (blocks [HIST,..)) ----------
#define HIST_BLOCKS 832
#define GEMM_BLOCKS 782   // ceil(50000/64)
__global__ __launch_bounds__(256) void heavy_kernel(
    const int* __restrict__ ei, int* __restrict__ deg, int* __restrict__ loc,
    const float* __restrict__ x, const u16* __restrict__ wt,
    const u16* __restrict__ w1t2, const float* __restrict__ bias,
    const float* __restrict__ b1,
    unsigned char* __restrict__ uxt, u16* __restrict__ vout)
{
  __shared__ u16 wl[128 * 128];  // 32KB, slot XOR-swizzled by (row&7)
  int bid = blockIdx.x;
  if (bid < HIST_BLOCKS) {
    // ----- histogram + per-edge rank; latency hides under GEMM blocks -----
    int stride = HIST_BLOCKS * 256;
    for (int e = bid * 256 + threadIdx.x; e < N_EDGES; e += stride)
      loc[e] = atomicAdd(&deg[clampi(ei[N_EDGES + e])], 1);
    return;
  }
  // ----- node GEMMs: xt(bf16), u(fp8), v(bf16); x read fp32 once -----
  int gb = bid - HIST_BLOCKS;
  int w = threadIdx.x >> 6, l = threadIdx.x & 63;
  int r2 = l & 15, q = l >> 4;
  int sw = r2 & 7;
  int rowbase = gb * 64 + w * 16;
  int ra = rowbase + r2;  if (ra >= N_NODES) ra = N_NODES - 1;
  bf16x8 A[4];
#pragma unroll
  for (int k = 0; k < 4; k++)
    A[k] = pack8(x + ra * F + q * 8 + 32 * k);

  // ---- phase 1: stage wt; xt = x@W + b -> uxt[.][128:384) bf16 ----
  for (int c = threadIdx.x; c < 128 * 16; c += 256) {
    int row = c >> 4, slot = c & 15;
    *(bf16x8*)&wl[row * 128 + ((slot ^ (row & 7)) << 3)] =
        *(const bf16x8*)(wt + row * 128 + slot * 8);
  }
  __syncthreads();
  {
    float bv[8];
#pragma unroll
    for (int nf = 0; nf < 8; nf++) bv[nf] = bias[r2 + 16 * nf];
    f32x4 acc[8] = {};
#pragma unroll
    for (int k = 0; k < 4; k++) {
#pragma unroll
      for (int nf = 0; nf < 8; nf++) {
        bf16x8 b = *(const bf16x8*)&wl[(16 * nf + r2) * 128 + (((q + 4 * k) ^ sw) << 3)];
        acc[nf] = __builtin_amdgcn_mfma_f32_16x16x32_bf16(A[k], b, acc[nf], 0, 0, 0);
      }
    }
#pragma unroll
    for (int nf = 0; nf < 8; nf++) {
#pragma unroll
      for (int r = 0; r < 4; r++) {
        int row = rowbase + 4 * q + r;
        int c = r2 + 16 * nf;
        if (row < N_NODES)
          *(u16*)(uxt + (size_t)row * ROWB + 128 + 2 * c) = f2bf(acc[nf][r] + bv[nf]);
      }
    }
  }
  __syncthreads();
  // ---- phase 2: stage W1s; u = x@W1s -> uxt[.][0:128) fp8 ----
  for (int c = threadIdx.x; c < 128 * 16; c += 256) {
    int row = c >> 4, slot = c & 15;
    *(bf16x8*)&wl[row * 128 + ((slot ^ (row & 7)) << 3)] =
        *(const bf16x8*)(w1t2 + row * 128 + slot * 8);
  }
  __syncthreads();
  {
    f32x4 acc[8] = {};
#pragma unroll
    for (int k = 0; k < 4; k++) {
#pragma unroll
      for (int nf = 0; nf < 8; nf++) {
        bf16x8 b = *(const bf16x8*)&wl[(16 * nf + r2) * 128 + (((q + 4 * k) ^ sw) << 3)];
        acc[nf] = __builtin_amdgcn_mfma_f32_16x16x32_bf16(A[k], b, acc[nf], 0, 0, 0);
      }
    }
#pragma unroll
    for (int nf = 0; nf < 8; nf++) {
#pragma unroll
      for (int r = 0; r < 4; r++) {
        int row = rowbase + 4 * q + r;
        int c = r2 + 16 * nf;
        if (row < N_NODES)
          uxt[(size_t)row * ROWB + c] = (unsigned char)f32_to_fp8(acc[nf][r]);
      }
    }
  }
  __syncthreads();
  // ---- phase 3: stage W1d; v = x@W1d + b1 -> vout bf16 ----
  for (int c = threadIdx.x; c < 128 * 16; c += 256) {
    int row = c >> 4, slot = c & 15;
    *(bf16x8*)&wl[row * 128 + ((slot ^ (row & 7)) << 3)] =
        *(const bf16x8*)(w1t2 + 128 * 128 + row * 128 + slot * 8);
  }
  __syncthreads();
  {
    float b1v[8];
#pragma unroll
    for (int nf = 0; nf < 8; nf++) b1v[nf] = b1[r2 + 16 * nf];
    f32x4 acc[8] = {};
#pragma unroll
    for (int k = 0; k < 4; k++) {
#pragma unroll
      for (int nf = 0; nf < 8; nf++) {
        bf16x8 b = *(const bf16x8*)&wl[(16 * nf + r2) * 128 + (((q + 4 * k) ^ sw) << 3)];
        acc[nf] = __builtin_amdgcn_mfma_f32_16x16x32_bf16(A[k], b, acc[nf], 0, 0, 0);
      }
    }
#pragma unroll
    for (int nf = 0; nf < 8; nf++) {
#pragma unroll
      for (int r = 0; r < 4; r++) {
        int row = rowbase + 4 * q + r;
        int c = r2 + 16 * nf;
        if (row < N_NODES) vout[row * F + c] = f2bf(acc[nf][r] + b1v[nf]);
      }
    }
  }
}

// ---------- hierarchical scan: 49-block partial scan ----------
#define SCAN_BLOCKS 49
__global__ __launch_bounds__(1024) void scan1_kernel(const int* __restrict__ deg,
                                                     int* __restrict__ offsets,
                                                     int* __restrict__ bsum) {
  __shared__ int wsum[16];
  int t = threadIdx.x, lane = t & 63, wid = t >> 6;
  int i = blockIdx.x * 1024 + t;
  int v = (i < N_NODES) ? deg[i] : 0;
  int s = v;
#pragma unroll
  for (int d = 1; d < 64; d <<= 1) {
    int u = __shfl_up(s, d);
    if (lane >= d) s += u;
  }
  if (lane == 63) wsum[wid] = s;
  __syncthreads();
  if (wid == 0 && lane < 16) {
    int ws = wsum[lane];
#pragma unroll
    for (int d = 1; d < 16; d <<= 1) {
      int u = __shfl_up(ws, d);
      if (lane >= d) ws += u;
    }
    wsum[lane] = ws;
  }
  __syncthreads();
  int wprev = (wid == 0) ? 0 : wsum[wid - 1];
  if (i < N_NODES) offsets[i] = wprev + s - v;  // block-local exclusive
  if (t == 0) bsum[blockIdx.x] = wsum[15];
}

// ---------- scan of block sums (redundant per block) + add base ----------
__global__ __launch_bounds__(256) void scan23_kernel(int* __restrict__ offsets,
                                                     const int* __restrict__ bsum) {
  __shared__ int base[SCAN_BLOCKS + 1];
  if (threadIdx.x < 64) {
    int t = threadIdx.x;
    int v = (t < SCAN_BLOCKS) ? bsum[t] : 0;
    int s = v;
#pragma unroll
    for (int d = 1; d < 64; d <<= 1) {
      int u = __shfl_up(s, d);
      if (t >= d) s += u;
    }
    if (t < SCAN_BLOCKS) base[t] = s - v;
    if (t == SCAN_BLOCKS - 1) base[SCAN_BLOCKS] = s;
  }
  __syncthreads();
  int i = blockIdx.x * blockDim.x + threadIdx.x;
  if (i < N_NODES) offsets[i] += base[i >> 10];
  if (i == 0) offsets[N_NODES] = base[SCAN_BLOCKS];
}

// ---------- reorder: atomic-free scatter, srcs16[offsets[d]+loc[e]] = src ----------
__global__ void reorder_kernel(const int* __restrict__ ei, const int* __restrict__ offsets,
                               const int* __restrict__ loc, u16* __restrict__ srcs16) {
  int e = blockIdx.x * blockDim.x + threadIdx.x;
  if (e < N_EDGES) {
    int s = clampi(ei[e]);
    int d = clampi(ei[N_EDGES + e]);
    srcs16[offsets[d] + loc[e]] = (u16)s;
  }
}

// ---------- fused gate + aggregate: one wave per dst node ----------
__global__ __launch_bounds__(256) void edge_fused_kernel(
    const unsigned char* __restrict__ uxt, const u16* __restrict__ v,
    const int* __restrict__ offsets, const u16* __restrict__ srcs16,
    const float* __restrict__ w2f, const float* __restrict__ b2,
    float* __restrict__ out)
{
  int n = (blockIdx.x * blockDim.x + threadIdx.x) >> 6;
  if (n >= N_NODES) return;
  int lane = threadIdx.x & 63;
  int g = lane >> 4, j = lane & 15;
  float w2v[8], vn[8];
  float4 wa = *(const float4*)(w2f + 8 * j);
  float4 wb = *(const float4*)(w2f + 8 * j + 4);
  w2v[0] = wa.x; w2v[1] = wa.y; w2v[2] = wa.z; w2v[3] = wa.w;
  w2v[4] = wb.x; w2v[5] = wb.y; w2v[6] = wb.z; w2v[7] = wb.w;
  bf16x8 vv = *(const bf16x8*)(v + n * F + 8 * j);
#pragma unroll
  for (int i = 0; i < 8; i++) vn[i] = (float)vv[i];
  float bias2 = b2[0];
  float acc[8] = {};
  int p = offsets[n], end = offsets[n + 1];
  for (int base = p; base < end; base += 4) {
    int slot = base + g;
    bool valid = slot < end;
    int sp = srcs16[valid ? slot : end - 1];
    const unsigned char* row = uxt + (size_t)sp * ROWB;
    uint2 up = *(const uint2*)(row + 8 * j);            // 8 fp8 u values
    bf16x8 xx = *(const bf16x8*)(row + 128 + 16 * j);   // 8 bf16 xt values
    f32x2 u01 = fp8x2_to_f32(up.x & 0xffffu);
    f32x2 u23 = fp8x2_to_f32(up.x >> 16);
    f32x2 u45 = fp8x2_to_f32(up.y & 0xffffu);
    f32x2 u67 = fp8x2_to_f32(up.y >> 16);
    float uu[8] = {u01[0], u01[1], u23[0], u23[1], u45[0], u45[1], u67[0], u67[1]};
    float t = 0.f;
#pragma unroll
    for (int i = 0; i < 8; i++) {
      float h = uu[i] + vn[i];
      h = h > 0.f ? h : 0.f;
      t += h * w2v[i];
    }
    t += __shfl_xor(t, 1);
    t += __shfl_xor(t, 2);
    t += __shfl_xor(t, 4);
    t += __shfl_xor(t, 8);
    float gate = valid ? 1.0f / (1.0f + __expf(-(t + bias2))) : 0.f;
#pragma unroll
    for (int i = 0; i < 8; i++) acc[i] += gate * (float)xx[i];
  }
#pragma unroll
  for (int i = 0; i < 8; i++) acc[i] += __shfl_xor(acc[i], 16);
#pragma unroll
  for (int i = 0; i < 8; i++) acc[i] += __shfl_xor(acc[i], 32);
  if (g == 0) {
    float4 o0, o1;
    o0.x = acc[0]; o0.y = acc[1]; o0.z = acc[2]; o0.w = acc[3];
    o1.x = acc[4]; o1.y = acc[5]; o1.z = acc[6]; o1.w = acc[7];
    *(float4*)(out + n * F + 8 * j) = o0;
    *(float4*)(out + n * F + 8 * j + 4) = o1;
  }
}

extern "C" void kernel_launch(void* const* d_in, const int* in_sizes, int n_in,
                              void* d_out, int out_size, void* d_ws, size_t ws_size,
                              hipStream_t stream) {
  const float* x  = (const float*)d_in[0];
  const int* ei   = (const int*)d_in[1];   // int64 in reference -> int32 in harness
  const float* W  = (const float*)d_in[2];
  const float* b  = (const float*)d_in[3];
  const float* W1 = (const float*)d_in[4];
  const float* b1 = (const float*)d_in[5];
  const float* W2 = (const float*)d_in[6];
  const float* b2 = (const float*)d_in[7];
  float* out = (float*)d_out;

  char* ws = (char*)d_ws;
  unsigned char* uxt = (unsigned char*)ws;    // 19,200,000 B  [n]: u fp8 | xt bf16
  u16* vout    = (u16*)(ws + 19200000);       // 12,800,000 B
  u16* wt      = (u16*)(ws + 32000000);       //     32,768 B
  u16* w1t2    = (u16*)(ws + 32032768);       //     65,536 B
  int* offsets = (int*)(ws + 32098304);       //    200,004 B
  int* deg     = (int*)(ws + 32298308);       //    200,000 B
  int* loc     = (int*)(ws + 32498308);       //  3,200,000 B
  u16* srcs16  = (u16*)(ws + 35698308);       //  1,600,000 B
  int* bsum    = (int*)(ws + 37298308);       //        196 B   total ~37.3 MB
  (void)ws_size;

  pre_kernel<<<ZERO_BLOCKS + PREP_BLOCKS, 256, 0, stream>>>(deg, W, W1, wt, w1t2);
  heavy_kernel<<<HIST_BLOCKS + GEMM_BLOCKS, 256, 0, stream>>>(
      ei, deg, loc, x, wt, w1t2, b, b1, uxt, vout);
  scan1_kernel<<<SCAN_BLOCKS, 1024, 0, stream>>>(deg, offsets, bsum);
  scan23_kernel<<<(N_NODES + 255) / 256, 256, 0, stream>>>(offsets, bsum);
  reorder_kernel<<<(N_EDGES + 255) / 256, 256, 0, stream>>>(ei, offsets, loc, srcs16);
  edge_fused_kernel<<<(N_NODES * 64 + 255) / 256, 256, 0, stream>>>(
      uxt, vout, offsets, srcs16, W2, b2, out);
}

// Round 15
// 125.950 us; speedup vs baseline: 5.6412x; 1.0093x over previous
//
#include <hip/hip_runtime.h>

#define N_NODES 50000
#define N_EDGES 800000
#define F 128
#define ROWB 384   // uxt row: [0,128)=u fp8, [128,384)=xt bf16

typedef unsigned short u16;
typedef __bf16 bf16x8 __attribute__((ext_vector_type(8)));
typedef float f32x4 __attribute__((ext_vector_type(4)));
typedef float f32x2 __attribute__((ext_vector_type(2)));

__device__ inline u16 f2bf(float f) {
  union { float f; unsigned u; } v; v.f = f;
  unsigned r = v.u + 0x7fffu + ((v.u >> 16) & 1u);
  return (u16)(r >> 16);
}

__device__ inline int clampi(int v) {
  v = v < 0 ? 0 : v;
  return v >= N_NODES ? N_NODES - 1 : v;
}

// fp8 e4m3 cvt via HW instruction (builtin if present, else inline asm)
__device__ inline f32x2 fp8x2_to_f32(unsigned w) {
#if __has_builtin(__builtin_amdgcn_cvt_pk_f32_fp8)
  return __builtin_amdgcn_cvt_pk_f32_fp8((int)w, false);
#else
  f32x2 r;
  asm("v_cvt_pk_f32_fp8 %0, %1" : "=v"(r) : "v"(w));
  return r;
#endif
}
__device__ inline unsigned f32_to_fp8(float a) {
#if __has_builtin(__builtin_amdgcn_cvt_pk_fp8_f32)
  return (unsigned)__builtin_amdgcn_cvt_pk_fp8_f32(a, a, 0, false) & 0xffu;
#else
  unsigned r;
  asm("v_cvt_pk_fp8_f32 %0, %1, %2" : "=v"(r) : "v"(a), "v"(a));
  return r & 0xffu;
#endif
}

// load 8 contiguous fp32 -> bf16x8 fragment
__device__ inline bf16x8 pack8(const float* __restrict__ p) {
  float4 a = *(const float4*)p;
  float4 b = *(const float4*)(p + 4);
  bf16x8 r;
  r[0] = (__bf16)a.x; r[1] = (__bf16)a.y; r[2] = (__bf16)a.z; r[3] = (__bf16)a.w;
  r[4] = (__bf16)b.x; r[5] = (__bf16)b.y; r[6] = (__bf16)b.z; r[7] = (__bf16)b.w;
  return r;
}

// ---------- pre: zero deg | transpose weights (disjoint block ranges) ----------
#define ZERO_BLOCKS 196
#define PREP_BLOCKS 192
__global__ __launch_bounds__(256) void pre_kernel(
    int* __restrict__ deg,
    const float* __restrict__ W, const float* __restrict__ W1,
    u16* __restrict__ wt, u16* __restrict__ w1t2)
{
  int bid = blockIdx.x;
  if (bid < ZERO_BLOCKS) {
    int i = bid * 256 + threadIdx.x;
    if (i < N_NODES) deg[i] = 0;
  } else {
    int t = (bid - ZERO_BLOCKS) * 256 + threadIdx.x;  // 0 .. 49151
    if (t < 128 * 128) {
      int k = t >> 7, n = t & 127;
      wt[n * 128 + k] = f2bf(W[k * 128 + n]);
    } else {
      int t2 = t - 128 * 128;           // 0 .. 32767
      int n2 = t2 >> 7, k = t2 & 127;   // n2: 0..255
      float v = (n2 < 128) ? W1[k * 128 + n2] : W1[(128 + k) * 128 + (n2 - 128)];
      w1t2[n2 * 128 + k] = f2bf(v);
    }
  }
}

// ---------- heavy: hist+loc (blocks [0,HIST)) | node GEMMs (blocks [HIST,..)) ----------
// __launch_bounds__(256,4): cap VGPR at ~128 so the GEMM branch does NOT spill
// (round 14: default alloc chose 64 VGPR -> 24MB scratch traffic, 57us).
#define HIST_BLOCKS 832
#define GEMM_BLOCKS 782   // ceil(50000/64)
__global__ __launch_bounds__(256, 4) void heavy_kernel(
    const int* __restrict__ ei, int* __restrict__ deg, int* __restrict__ loc,
    const float* __restrict__ x, const u16* __restrict__ wt,
    const u16* __restrict__ w1t2, const float* __restrict__ bias,
    const float* __restrict__ b1,
    unsigned char* __restrict__ uxt, u16* __restrict__ vout)
{
  __shared__ u16 wl[128 * 128];  // 32KB, slot XOR-swizzled by (row&7)
  int bid = blockIdx.x;
  if (bid < HIST_BLOCKS) {
    // ----- histogram + per-edge rank; latency hides under GEMM blocks -----
    int stride = HIST_BLOCKS * 256;
    for (int e = bid * 256 + threadIdx.x; e < N_EDGES; e += stride)
      loc[e] = atomicAdd(&deg[clampi(ei[N_EDGES + e])], 1);
    return;
  }
  // ----- node GEMMs: xt(bf16), u(fp8), v(bf16); x read fp32 once -----
  int gb = bid - HIST_BLOCKS;
  int w = threadIdx.x >> 6, l = threadIdx.x & 63;
  int r2 = l & 15, q = l >> 4;
  int sw = r2 & 7;
  int rowbase = gb * 64 + w * 16;
  int ra = rowbase + r2;  if (ra >= N_NODES) ra = N_NODES - 1;
  bf16x8 A[4];
#pragma unroll
  for (int k = 0; k < 4; k++)
    A[k] = pack8(x + ra * F + q * 8 + 32 * k);

  // ---- phase 1: stage wt; xt = x@W + b -> uxt[.][128:384) bf16 ----
  for (int c = threadIdx.x; c < 128 * 16; c += 256) {
    int row = c >> 4, slot = c & 15;
    *(bf16x8*)&wl[row * 128 + ((slot ^ (row & 7)) << 3)] =
        *(const bf16x8*)(wt + row * 128 + slot * 8);
  }
  __syncthreads();
  {
    float bv[8];
#pragma unroll
    for (int nf = 0; nf < 8; nf++) bv[nf] = bias[r2 + 16 * nf];
    f32x4 acc[8] = {};
#pragma unroll
    for (int k = 0; k < 4; k++) {
#pragma unroll
      for (int nf = 0; nf < 8; nf++) {
        bf16x8 b = *(const bf16x8*)&wl[(16 * nf + r2) * 128 + (((q + 4 * k) ^ sw) << 3)];
        acc[nf] = __builtin_amdgcn_mfma_f32_16x16x32_bf16(A[k], b, acc[nf], 0, 0, 0);
      }
    }
#pragma unroll
    for (int nf = 0; nf < 8; nf++) {
#pragma unroll
      for (int r = 0; r < 4; r++) {
        int row = rowbase + 4 * q + r;
        int c = r2 + 16 * nf;
        if (row < N_NODES)
          *(u16*)(uxt + (size_t)row * ROWB + 128 + 2 * c) = f2bf(acc[nf][r] + bv[nf]);
      }
    }
  }
  __syncthreads();
  // ---- phase 2: stage W1s; u = x@W1s -> uxt[.][0:128) fp8 ----
  for (int c = threadIdx.x; c < 128 * 16; c += 256) {
    int row = c >> 4, slot = c & 15;
    *(bf16x8*)&wl[row * 128 + ((slot ^ (row & 7)) << 3)] =
        *(const bf16x8*)(w1t2 + row * 128 + slot * 8);
  }
  __syncthreads();
  {
    f32x4 acc[8] = {};
#pragma unroll
    for (int k = 0; k < 4; k++) {
#pragma unroll
      for (int nf = 0; nf < 8; nf++) {
        bf16x8 b = *(const bf16x8*)&wl[(16 * nf + r2) * 128 + (((q + 4 * k) ^ sw) << 3)];
        acc[nf] = __builtin_amdgcn_mfma_f32_16x16x32_bf16(A[k], b, acc[nf], 0, 0, 0);
      }
    }
#pragma unroll
    for (int nf = 0; nf < 8; nf++) {
#pragma unroll
      for (int r = 0; r < 4; r++) {
        int row = rowbase + 4 * q + r;
        int c = r2 + 16 * nf;
        if (row < N_NODES)
          uxt[(size_t)row * ROWB + c] = (unsigned char)f32_to_fp8(acc[nf][r]);
      }
    }
  }
  __syncthreads();
  // ---- phase 3: stage W1d; v = x@W1d + b1 -> vout bf16 ----
  for (int c = threadIdx.x; c < 128 * 16; c += 256) {
    int row = c >> 4, slot = c & 15;
    *(bf16x8*)&wl[row * 128 + ((slot ^ (row & 7)) << 3)] =
        *(const bf16x8*)(w1t2 + 128 * 128 + row * 128 + slot * 8);
  }
  __syncthreads();
  {
    float b1v[8];
#pragma unroll
    for (int nf = 0; nf < 8; nf++) b1v[nf] = b1[r2 + 16 * nf];
    f32x4 acc[8] = {};
#pragma unroll
    for (int k = 0; k < 4; k++) {
#pragma unroll
      for (int nf = 0; nf < 8; nf++) {
        bf16x8 b = *(const bf16x8*)&wl[(16 * nf + r2) * 128 + (((q + 4 * k) ^ sw) << 3)];
        acc[nf] = __builtin_amdgcn_mfma_f32_16x16x32_bf16(A[k], b, acc[nf], 0, 0, 0);
      }
    }
#pragma unroll
    for (int nf = 0; nf < 8; nf++) {
#pragma unroll
      for (int r = 0; r < 4; r++) {
        int row = rowbase + 4 * q + r;
        int c = r2 + 16 * nf;
        if (row < N_NODES) vout[row * F + c] = f2bf(acc[nf][r] + b1v[nf]);
      }
    }
  }
}

// ---------- hierarchical scan: 49-block partial scan ----------
#define SCAN_BLOCKS 49
__global__ __launch_bounds__(1024) void scan1_kernel(const int* __restrict__ deg,
                                                     int* __restrict__ offsets,
                                                     int* __restrict__ bsum) {
  __shared__ int wsum[16];
  int t = threadIdx.x, lane = t & 63, wid = t >> 6;
  int i = blockIdx.x * 1024 + t;
  int v = (i < N_NODES) ? deg[i] : 0;
  int s = v;
#pragma unroll
  for (int d = 1; d < 64; d <<= 1) {
    int u = __shfl_up(s, d);
    if (lane >= d) s += u;
  }
  if (lane == 63) wsum[wid] = s;
  __syncthreads();
  if (wid == 0 && lane < 16) {
    int ws = wsum[lane];
#pragma unroll
    for (int d = 1; d < 16; d <<= 1) {
      int u = __shfl_up(ws, d);
      if (lane >= d) ws += u;
    }
    wsum[lane] = ws;
  }
  __syncthreads();
  int wprev = (wid == 0) ? 0 : wsum[wid - 1];
  if (i < N_NODES) offsets[i] = wprev + s - v;  // block-local exclusive
  if (t == 0) bsum[blockIdx.x] = wsum[15];
}

// ---------- scan of block sums (redundant per block) + add base ----------
__global__ __launch_bounds__(256) void scan23_kernel(int* __restrict__ offsets,
                                                     const int* __restrict__ bsum) {
  __shared__ int base[SCAN_BLOCKS + 1];
  if (threadIdx.x < 64) {
    int t = threadIdx.x;
    int v = (t < SCAN_BLOCKS) ? bsum[t] : 0;
    int s = v;
#pragma unroll
    for (int d = 1; d < 64; d <<= 1) {
      int u = __shfl_up(s, d);
      if (t >= d) s += u;
    }
    if (t < SCAN_BLOCKS) base[t] = s - v;
    if (t == SCAN_BLOCKS - 1) base[SCAN_BLOCKS] = s;
  }
  __syncthreads();
  int i = blockIdx.x * blockDim.x + threadIdx.x;
  if (i < N_NODES) offsets[i] += base[i >> 10];
  if (i == 0) offsets[N_NODES] = base[SCAN_BLOCKS];
}

// ---------- reorder: atomic-free scatter, srcs16[offsets[d]+loc[e]] = src ----------
__global__ void reorder_kernel(const int* __restrict__ ei, const int* __restrict__ offsets,
                               const int* __restrict__ loc, u16* __restrict__ srcs16) {
  int e = blockIdx.x * blockDim.x + threadIdx.x;
  if (e < N_EDGES) {
    int s = clampi(ei[e]);
    int d = clampi(ei[N_EDGES + e]);
    srcs16[offsets[d] + loc[e]] = (u16)s;
  }
}

// ---------- fused gate + aggregate: one wave per dst node ----------
__global__ __launch_bounds__(256) void edge_fused_kernel(
    const unsigned char* __restrict__ uxt, const u16* __restrict__ v,
    const int* __restrict__ offsets, const u16* __restrict__ srcs16,
    const float* __restrict__ w2f, const float* __restrict__ b2,
    float* __restrict__ out)
{
  int n = (blockIdx.x * blockDim.x + threadIdx.x) >> 6;
  if (n >= N_NODES) return;
  int lane = threadIdx.x & 63;
  int g = lane >> 4, j = lane & 15;
  float w2v[8], vn[8];
  float4 wa = *(const float4*)(w2f + 8 * j);
  float4 wb = *(const float4*)(w2f + 8 * j + 4);
  w2v[0] = wa.x; w2v[1] = wa.y; w2v[2] = wa.z; w2v[3] = wa.w;
  w2v[4] = wb.x; w2v[5] = wb.y; w2v[6] = wb.z; w2v[7] = wb.w;
  bf16x8 vv = *(const bf16x8*)(v + n * F + 8 * j);
#pragma unroll
  for (int i = 0; i < 8; i++) vn[i] = (float)vv[i];
  float bias2 = b2[0];
  float acc[8] = {};
  int p = offsets[n], end = offsets[n + 1];
  for (int base = p; base < end; base += 4) {
    int slot = base + g;
    bool valid = slot < end;
    int sp = srcs16[valid ? slot : end - 1];
    const unsigned char* row = uxt + (size_t)sp * ROWB;
    uint2 up = *(const uint2*)(row + 8 * j);            // 8 fp8 u values
    bf16x8 xx = *(const bf16x8*)(row + 128 + 16 * j);   // 8 bf16 xt values
    f32x2 u01 = fp8x2_to_f32(up.x & 0xffffu);
    f32x2 u23 = fp8x2_to_f32(up.x >> 16);
    f32x2 u45 = fp8x2_to_f32(up.y & 0xffffu);
    f32x2 u67 = fp8x2_to_f32(up.y >> 16);
    float uu[8] = {u01[0], u01[1], u23[0], u23[1], u45[0], u45[1], u67[0], u67[1]};
    float t = 0.f;
#pragma unroll
    for (int i = 0; i < 8; i++) {
      float h = uu[i] + vn[i];
      h = h > 0.f ? h : 0.f;
      t += h * w2v[i];
    }
    t += __shfl_xor(t, 1);
    t += __shfl_xor(t, 2);
    t += __shfl_xor(t, 4);
    t += __shfl_xor(t, 8);
    float gate = valid ? 1.0f / (1.0f + __expf(-(t + bias2))) : 0.f;
#pragma unroll
    for (int i = 0; i < 8; i++) acc[i] += gate * (float)xx[i];
  }
#pragma unroll
  for (int i = 0; i < 8; i++) acc[i] += __shfl_xor(acc[i], 16);
#pragma unroll
  for (int i = 0; i < 8; i++) acc[i] += __shfl_xor(acc[i], 32);
  if (g == 0) {
    float4 o0, o1;
    o0.x = acc[0]; o0.y = acc[1]; o0.z = acc[2]; o0.w = acc[3];
    o1.x = acc[4]; o1.y = acc[5]; o1.z = acc[6]; o1.w = acc[7];
    *(float4*)(out + n * F + 8 * j) = o0;
    *(float4*)(out + n * F + 8 * j + 4) = o1;
  }
}

extern "C" void kernel_launch(void* const* d_in, const int* in_sizes, int n_in,
                              void* d_out, int out_size, void* d_ws, size_t ws_size,
                              hipStream_t stream) {
  const float* x  = (const float*)d_in[0];
  const int* ei   = (const int*)d_in[1];   // int64 in reference -> int32 in harness
  const float* W  = (const float*)d_in[2];
  const float* b  = (const float*)d_in[3];
  const float* W1 = (const float*)d_in[4];
  const float* b1 = (const float*)d_in[5];
  const float* W2 = (const float*)d_in[6];
  const float* b2 = (const float*)d_in[7];
  float* out = (float*)d_out;

  char* ws = (char*)d_ws;
  unsigned char* uxt = (unsigned char*)ws;    // 19,200,000 B  [n]: u fp8 | xt bf16
  u16* vout    = (u16*)(ws + 19200000);       // 12,800,000 B
  u16* wt      = (u16*)(ws + 32000000);       //     32,768 B
  u16* w1t2    = (u16*)(ws + 32032768);       //     65,536 B
  int* offsets = (int*)(ws + 32098304);       //    200,004 B
  int* deg     = (int*)(ws + 32298308);       //    200,000 B
  int* loc     = (int*)(ws + 32498308);       //  3,200,000 B
  u16* srcs16  = (u16*)(ws + 35698308);       //  1,600,000 B
  int* bsum    = (int*)(ws + 37298308);       //        196 B   total ~37.3 MB
  (void)ws_size;

  pre_kernel<<<ZERO_BLOCKS + PREP_BLOCKS, 256, 0, stream>>>(deg, W, W1, wt, w1t2);
  heavy_kernel<<<HIST_BLOCKS + GEMM_BLOCKS, 256, 0, stream>>>(
      ei, deg, loc, x, wt, w1t2, b, b1, uxt, vout);
  scan1_kernel<<<SCAN_BLOCKS, 1024, 0, stream>>>(deg, offsets, bsum);
  scan23_kernel<<<(N_NODES + 255) / 256, 256, 0, stream>>>(offsets, bsum);
  reorder_kernel<<<(N_EDGES + 255) / 256, 256, 0, stream>>>(ei, offsets, loc, srcs16);
  edge_fused_kernel<<<(N_NODES * 64 + 255) / 256, 256, 0, stream>>>(
      uxt, vout, offsets, srcs16, W2, b2, out);
}